// Round 8
// baseline (787.352 us; speedup 1.0000x reference)
//
#include <hip/hip_runtime.h>
#include <cstdint>
#include <cstddef>

// ============================================================================
// ViT block: LN1 -> (QKV + LoRA) -> 14x14 windowed attention (decomposed
// rel-pos bias) -> proj + residual -> LN2 -> MLP (fast-tanh GELU) + residual.
//
// GEMM assignment (r8, ledger-driven):
//  - QKV, MLP-up: gemm8p_v4 (r6 config, best measured). v5 deep-prefetch
//    RETIRED (r7: burst-issuing 8 GLDS at ph0 congests TA/TCP at 1 block/CU;
//    -12 us vs v4's 2-per-phase spread).
//  - proj, MLP-down: proven 128-tile 2-barrier m97 kernel (split-K / BM=64 /
//    256-tile variants all retired by r3-r5 measurements).
//  - attn (r8 experiment): V NO LONGER LDS-STAGED -- read direct from L2
//    (26 KB/block, L2-resident; guide common-mistake #7). LDS 70.4->40.7 KB
//    -> 3 blocks/CU (12 waves/CU): grid 800 runs in ~1.04 rounds instead of
//    1.56 (tail-fill) and extra waves hide the global-V latency.
// qkv buffer layout: slot(bw,which,h) stride 13312 elements.
//   Q,K: [tok(208 pad)][64]   V: [64][tok(208 pad)]  (pre-transposed)
// ============================================================================

typedef __bf16 bf16x8 __attribute__((ext_vector_type(8)));
typedef float f32x4 __attribute__((ext_vector_type(4)));

__device__ __forceinline__ unsigned short f2bf(float f) {
    unsigned u = __float_as_uint(f);
    u = (u + 0x7fffu + ((u >> 16) & 1u)) >> 16;
    return (unsigned short)u;
}
__device__ __forceinline__ float bf2f(unsigned short h) {
    return __uint_as_float(((unsigned)h) << 16);
}

// async global->LDS, 16B per lane. LDS layout must be uniform_base + lane*16.
#define GLDS16(gp, lp) __builtin_amdgcn_global_load_lds( \
    (__attribute__((address_space(1))) unsigned int*)(gp), \
    (__attribute__((address_space(3))) unsigned int*)(lp), 16, 0, 0)

// ---------------------------------------------------------------------------
// Weight prep: W_effT[n][k] = qkv_w[k][n] + 2 * sum_r lora_a[k][r]*lora_b[r][n]
// ---------------------------------------------------------------------------
__global__ __launch_bounds__(256) void weff_kernel(
    const float* __restrict__ W, const float* __restrict__ la,
    const float* __restrict__ lb, unsigned short* __restrict__ Wt)
{
    __shared__ float tile[32][33];
    __shared__ float lat[32][16];
    __shared__ float lbt[16][32];
    const int kb = blockIdx.x * 32, nb = blockIdx.y * 32;
    const int tn = threadIdx.x & 31, tk = threadIdx.x >> 5;
    for (int i = threadIdx.x; i < 32 * 16; i += 256)
        lat[i >> 4][i & 15] = la[(size_t)(kb + (i >> 4)) * 16 + (i & 15)];
    for (int i = threadIdx.x; i < 16 * 32; i += 256)
        lbt[i >> 5][i & 31] = lb[(size_t)(i >> 5) * 3072 + nb + (i & 31)];
#pragma unroll
    for (int i = 0; i < 4; ++i) {
        int k = tk + i * 8;
        tile[k][tn] = W[(size_t)(kb + k) * 3072 + nb + tn];
    }
    __syncthreads();
#pragma unroll
    for (int i = 0; i < 4; ++i) {
        int n = tk + i * 8;
        float acc = tile[tn][n];
#pragma unroll
        for (int r = 0; r < 16; ++r) acc += 2.0f * lat[tn][r] * lbt[r][n];
        Wt[(size_t)(nb + n) * 1024 + kb + tn] = f2bf(acc);
    }
}

// ---------------------------------------------------------------------------
// Fused 3-way transpose: fp32 (KxN) -> bf16 (NxK) for proj_w / w1 / w2.
// ---------------------------------------------------------------------------
__global__ __launch_bounds__(256) void transpose3_kernel(
    const float* __restrict__ Wp, unsigned short* __restrict__ WpT,
    const float* __restrict__ W1, unsigned short* __restrict__ W1T,
    const float* __restrict__ W2, unsigned short* __restrict__ W2T)
{
    __shared__ float tile[32][33];
    const int id = blockIdx.x;
    const float* W; unsigned short* Wt; int Kdim, Ndim, kb, nb;
    if (id < 1024)      { W = Wp; Wt = WpT; Kdim = 1024; Ndim = 1024; const int t = id;        kb = t >> 5; nb = t & 31; }
    else if (id < 5120) { W = W1; Wt = W1T; Kdim = 1024; Ndim = 4096; const int t = id - 1024; kb = t >> 7; nb = t & 127; }
    else                { W = W2; Wt = W2T; Kdim = 4096; Ndim = 1024; const int t = id - 5120; kb = t >> 5; nb = t & 31; }
    kb <<= 5; nb <<= 5;
    const int tn = threadIdx.x & 31, tk = threadIdx.x >> 5;
#pragma unroll
    for (int i = 0; i < 4; ++i) {
        int k = tk + i * 8;
        tile[k][tn] = W[(size_t)(kb + k) * Ndim + nb + tn];
    }
    __syncthreads();
#pragma unroll
    for (int i = 0; i < 4; ++i) {
        int n = tk + i * 8;
        Wt[(size_t)(nb + n) * Kdim + kb + tn] = f2bf(tile[tn][n]);
    }
}

// ---------------------------------------------------------------------------
// LN1: x (2,64,64,1024) fp32 -> windowed bf16 (50*196, 1024); pad tokens = 0.
// ---------------------------------------------------------------------------
__global__ __launch_bounds__(256) void ln1_kernel(
    const float* __restrict__ x, const float* __restrict__ g,
    const float* __restrict__ b, unsigned short* __restrict__ out)
{
    const int blk = blockIdx.x;             // 0..9799
    const int tid = threadIdx.x;
    const int bw = blk / 196, tok = blk - bw * 196;
    const int bat = bw / 25, rw = bw - bat * 25;
    const int wy = rw / 5, wx = rw - wy * 5;
    const int ty = tok / 14, tx = tok - ty * 14;
    const int y = wy * 14 + ty, xx = wx * 14 + tx;
    unsigned short* orow = out + (size_t)blk * 1024;
    if (y >= 64 || xx >= 64) {
        *(uint2*)(orow + tid * 4) = make_uint2(0u, 0u);
        return;
    }
    const float* irow = x + ((size_t)((bat * 64 + y) * 64 + xx)) * 1024;
    const float4 v = *(const float4*)(irow + tid * 4);
    float s = v.x + v.y + v.z + v.w;
    float ss = v.x * v.x + v.y * v.y + v.z * v.z + v.w * v.w;
    for (int o = 32; o > 0; o >>= 1) { s += __shfl_xor(s, o); ss += __shfl_xor(ss, o); }
    __shared__ float red[8];
    const int wave = tid >> 6, lane = tid & 63;
    if (lane == 0) { red[wave] = s; red[4 + wave] = ss; }
    __syncthreads();
    s = red[0] + red[1] + red[2] + red[3];
    ss = red[4] + red[5] + red[6] + red[7];
    const float mu = s * (1.0f / 1024.0f);
    const float var = ss * (1.0f / 1024.0f) - mu * mu;
    const float rstd = rsqrtf(var + 1e-6f);
    const float4 gv = *(const float4*)(g + tid * 4);
    const float4 bv = *(const float4*)(b + tid * 4);
    const float a0 = (v.x - mu) * rstd * gv.x + bv.x;
    const float a1 = (v.y - mu) * rstd * gv.y + bv.y;
    const float a2 = (v.z - mu) * rstd * gv.z + bv.z;
    const float a3 = (v.w - mu) * rstd * gv.w + bv.w;
    const unsigned r0 = (unsigned)f2bf(a0) | ((unsigned)f2bf(a1) << 16);
    const unsigned r1 = (unsigned)f2bf(a2) | ((unsigned)f2bf(a3) << 16);
    *(uint2*)(orow + tid * 4) = make_uint2(r0, r1);
}

// LN2: rows of x1 (d_out, fp32) -> bf16, 8192 rows
__global__ __launch_bounds__(256) void ln2_kernel(
    const float* __restrict__ x, const float* __restrict__ g,
    const float* __restrict__ b, unsigned short* __restrict__ out)
{
    const int blk = blockIdx.x;
    const int tid = threadIdx.x;
    const float* irow = x + (size_t)blk * 1024;
    unsigned short* orow = out + (size_t)blk * 1024;
    const float4 v = *(const float4*)(irow + tid * 4);
    float s = v.x + v.y + v.z + v.w;
    float ss = v.x * v.x + v.y * v.y + v.z * v.z + v.w * v.w;
    for (int o = 32; o > 0; o >>= 1) { s += __shfl_xor(s, o); ss += __shfl_xor(ss, o); }
    __shared__ float red[8];
    const int wave = tid >> 6, lane = tid & 63;
    if (lane == 0) { red[wave] = s; red[4 + wave] = ss; }
    __syncthreads();
    s = red[0] + red[1] + red[2] + red[3];
    ss = red[4] + red[5] + red[6] + red[7];
    const float mu = s * (1.0f / 1024.0f);
    const float var = ss * (1.0f / 1024.0f) - mu * mu;
    const float rstd = rsqrtf(var + 1e-6f);
    const float4 gv = *(const float4*)(g + tid * 4);
    const float4 bv = *(const float4*)(b + tid * 4);
    const float a0 = (v.x - mu) * rstd * gv.x + bv.x;
    const float a1 = (v.y - mu) * rstd * gv.y + bv.y;
    const float a2 = (v.z - mu) * rstd * gv.z + bv.z;
    const float a3 = (v.w - mu) * rstd * gv.w + bv.w;
    const unsigned r0 = (unsigned)f2bf(a0) | ((unsigned)f2bf(a1) << 16);
    const unsigned r1 = (unsigned)f2bf(a2) | ((unsigned)f2bf(a3) << 16);
    *(uint2*)(orow + tid * 4) = make_uint2(r0, r1);
}

// ---------------------------------------------------------------------------
// gemm8p_v4: C[m][n] = sum_k A[m][k] * Bt[n][k]; BM=BN=256, BK=64, 512 thr.
// 4 phases/K-tile with B-register reuse (reads 8/4/8/4), counted vmcnt(2)
// mid+boundary, stage order {B01|B23|A02|A13}; LDS slot = chunk^(row&7)
// (0 conflicts, verified r3); inverse swizzle on per-lane global source.
// ---------------------------------------------------------------------------
template <int EPI>
__global__ __launch_bounds__(512, 2) void gemm8p_v4(
    const unsigned short* __restrict__ A,
    const unsigned short* __restrict__ Bt,
    const float* __restrict__ bias,
    void* __restrict__ outp,
    int M, int K, int nbm, int nbn)
{
    __shared__ unsigned short As_s[2 * 16384];
    __shared__ unsigned short Bs_s[2 * 16384];

    const int tid = threadIdx.x;
    const int wave = tid >> 6, lane = tid & 63;
    const int lr = lane & 15, lq = lane >> 4;

    const int ss = (nbm + 7) >> 3;
    const int xcd = blockIdx.x & 7;
    const int sidx = blockIdx.x >> 3;
    const int ntl = sidx / ss;
    const int m_loc = sidx - ntl * ss;
    const int mt = xcd * ss + m_loc;
    if (mt >= nbm) return;
    const int m_base = mt * 256, n_base = ntl * 256;
    const int NT = K >> 6;

    const int wm = (wave >> 2) * 128;           // 2 m-groups
    const int wn = (wave & 3) * 64;             // 4 n-groups

    // --- staging pointers: thread covers (row u*64 + tid>>3, slot tid&7) ---
    const int srow = tid >> 3, sslot = tid & 7;
    const int gch = sslot ^ (srow & 7);          // inverse swizzle on source
    const unsigned short* a_gp[4];
    const unsigned short* b_gp[4];
#pragma unroll
    for (int u = 0; u < 4; ++u) {
        int ar = m_base + u * 64 + srow; ar = ar < M ? ar : M - 1;
        a_gp[u] = A + (size_t)ar * K + gch * 8;
        b_gp[u] = Bt + (size_t)(n_base + u * 64 + srow) * K + gch * 8;
    }
#define STG_A(t, u) GLDS16(a_gp[u] + (size_t)(t) * 64, As_s + (((t) & 1) << 14) + (u) * 4096 + tid * 8)
#define STG_B(t, u) GLDS16(b_gp[u] + (size_t)(t) * 64, Bs_s + (((t) & 1) << 14) + (u) * 4096 + tid * 8)

    // --- fragment read offsets (shorts): row*64 + slot*8, slot = chunk^(lr&7)
    const int sl0 = lq ^ (lr & 7);               // kh0 slot; kh1 = sl0 ^ 4
    const int a_off = (wm + lr) * 64 + sl0 * 8;  // ^32 toggles k-half
    const int b_off = (wn + lr) * 64 + sl0 * 8;

    f32x4 acc[8][4] = {};

    // --- prologue: tile 0, {B all, A-u0,u2} first, then A-u1,u3 ---
    STG_B(0, 0); STG_B(0, 1); STG_B(0, 2); STG_B(0, 3);
    STG_A(0, 0); STG_A(0, 2);
    STG_A(0, 1); STG_A(0, 3);
    asm volatile("s_waitcnt vmcnt(2)" ::: "memory");
    __builtin_amdgcn_s_barrier();

    for (int t = 0; t < NT; ++t) {
        const unsigned short* Ab = As_s + ((t & 1) << 14);
        const unsigned short* Bb = Bs_s + ((t & 1) << 14);
        bf16x8 af[4], bfv[4];
        // ---- ph0: af[0..3] + bf, kh0; stage B-u0,u1(t+1); mid vmcnt ----
#pragma unroll
        for (int mf = 0; mf < 4; ++mf) af[mf] = *(const bf16x8*)(Ab + a_off + mf * 1024);
#pragma unroll
        for (int nf = 0; nf < 4; ++nf) bfv[nf] = *(const bf16x8*)(Bb + b_off + nf * 1024);
        if (t + 1 < NT) { STG_B(t + 1, 0); STG_B(t + 1, 1); }
        __builtin_amdgcn_s_barrier();
        asm volatile("s_waitcnt lgkmcnt(0)" ::: "memory");
        __builtin_amdgcn_sched_barrier(0);
        __builtin_amdgcn_s_setprio(1);
#pragma unroll
        for (int mf = 0; mf < 4; ++mf)
#pragma unroll
            for (int nf = 0; nf < 4; ++nf)
                acc[mf][nf] = __builtin_amdgcn_mfma_f32_16x16x32_bf16(af[mf], bfv[nf], acc[mf][nf], 0, 0, 0);
        __builtin_amdgcn_s_setprio(0);
        if (t == NT - 1) { asm volatile("s_waitcnt vmcnt(0)" ::: "memory"); }
        else             { asm volatile("s_waitcnt vmcnt(2)" ::: "memory"); }
        __builtin_amdgcn_s_barrier();
        // ---- ph1: af[4..7] kh0 (bfv reused); stage B-u2,u3(t+1) ----
#pragma unroll
        for (int mf = 0; mf < 4; ++mf) af[mf] = *(const bf16x8*)(Ab + a_off + (4 + mf) * 1024);
        if (t + 1 < NT) { STG_B(t + 1, 2); STG_B(t + 1, 3); }
        __builtin_amdgcn_s_barrier();
        asm volatile("s_waitcnt lgkmcnt(0)" ::: "memory");
        __builtin_amdgcn_sched_barrier(0);
        __builtin_amdgcn_s_setprio(1);
#pragma unroll
        for (int mf = 0; mf < 4; ++mf)
#pragma unroll
            for (int nf = 0; nf < 4; ++nf)
                acc[4 + mf][nf] = __builtin_amdgcn_mfma_f32_16x16x32_bf16(af[mf], bfv[nf], acc[4 + mf][nf], 0, 0, 0);
        __builtin_amdgcn_s_setprio(0);
        __builtin_amdgcn_s_barrier();
        // ---- ph2: af[0..3] + bf, kh1; stage A-u0,u2(t+1) ----
#pragma unroll
        for (int mf = 0; mf < 4; ++mf) af[mf] = *(const bf16x8*)(Ab + (a_off ^ 32) + mf * 1024);
#pragma unroll
        for (int nf = 0; nf < 4; ++nf) bfv[nf] = *(const bf16x8*)(Bb + (b_off ^ 32) + nf * 1024);
        if (t + 1 < NT) { STG_A(t + 1, 0); STG_A(t + 1, 2); }
        __builtin_amdgcn_s_barrier();
        asm volatile("s_waitcnt lgkmcnt(0)" ::: "memory");
        __builtin_amdgcn_sched_barrier(0);
        __builtin_amdgcn_s_setprio(1);
#pragma unroll
        for (int mf = 0; mf < 4; ++mf)
#pragma unroll
            for (int nf = 0; nf < 4; ++nf)
                acc[mf][nf] = __builtin_amdgcn_mfma_f32_16x16x32_bf16(af[mf], bfv[nf], acc[mf][nf], 0, 0, 0);
        __builtin_amdgcn_s_setprio(0);
        __builtin_amdgcn_s_barrier();
        // ---- ph3: af[4..7] kh1 (bfv reused); stage A-u1,u3(t+1); bnd vmcnt ----
#pragma unroll
        for (int mf = 0; mf < 4; ++mf) af[mf] = *(const bf16x8*)(Ab + (a_off ^ 32) + (4 + mf) * 1024);
        if (t + 1 < NT) { STG_A(t + 1, 1); STG_A(t + 1, 3); }
        __builtin_amdgcn_s_barrier();
        asm volatile("s_waitcnt lgkmcnt(0)" ::: "memory");
        __builtin_amdgcn_sched_barrier(0);
        __builtin_amdgcn_s_setprio(1);
#pragma unroll
        for (int mf = 0; mf < 4; ++mf)
#pragma unroll
            for (int nf = 0; nf < 4; ++nf)
                acc[4 + mf][nf] = __builtin_amdgcn_mfma_f32_16x16x32_bf16(af[mf], bfv[nf], acc[4 + mf][nf], 0, 0, 0);
        __builtin_amdgcn_s_setprio(0);
        if (t < NT - 1) { asm volatile("s_waitcnt vmcnt(2)" ::: "memory"); }
        __builtin_amdgcn_s_barrier();
    }
#undef STG_A
#undef STG_B

    // ------------------------------- epilogue -------------------------------
    float biasv[4];
#pragma unroll
    for (int j = 0; j < 4; ++j) biasv[j] = bias[n_base + wn + j * 16 + lr];

    if constexpr (EPI == 0) {
        // qkv scatter; V written transposed, packed 4 tokens (8B) per store.
        // 196 % 4 == 0 and row-starts % 4 == 0 -> 4-row chunk never straddles.
#pragma unroll
        for (int i = 0; i < 8; ++i) {
            const int m0i = m_base + wm + i * 16 + lq * 4;
            if (m0i >= M) continue;
            const int bw = m0i / 196, tok0 = m0i - bw * 196;
#pragma unroll
            for (int j = 0; j < 4; ++j) {
                const int n = n_base + wn + j * 16 + lr;
                const int which = n >> 10, hh = (n >> 6) & 15, d = n & 63;
                unsigned short* slotp = (unsigned short*)outp + (size_t)((bw * 3 + which) * 16 + hh) * 13312;
                if (which == 2) {
                    unsigned long long pv = 0;
#pragma unroll
                    for (int r = 0; r < 4; ++r)
                        pv |= (unsigned long long)f2bf(acc[i][j][r] + biasv[j]) << (16 * r);
                    *(unsigned long long*)(slotp + (size_t)d * 208 + tok0) = pv;
                } else {
#pragma unroll
                    for (int r = 0; r < 4; ++r)
                        slotp[(size_t)(tok0 + r) * 64 + d] = f2bf(acc[i][j][r] + biasv[j]);
                }
            }
        }
    } else {
        // EPI == 2: fast tanh-GELU -> bf16 [M][4096]
#pragma unroll
        for (int i = 0; i < 8; ++i) {
#pragma unroll
            for (int r = 0; r < 4; ++r) {
                const int m = m_base + wm + i * 16 + lq * 4 + r;
                if (m >= M) continue;
#pragma unroll
                for (int j = 0; j < 4; ++j) {
                    const int n = n_base + wn + j * 16 + lr;
                    const float v = acc[i][j][r] + biasv[j];
                    const float t2 = 1.5957691216f * (v + 0.044715f * v * v * v);
                    const float e = __expf(-t2);
                    const float gl = v * __builtin_amdgcn_rcpf(1.0f + e);
                    ((unsigned short*)outp)[(size_t)m * 4096 + n] = f2bf(gl);
                }
            }
        }
    }
}

// ---------------------------------------------------------------------------
// Proven 128-tile 2-barrier GEMM (m97 structure) — proj and MLP-down.
// EPI=1: proj (bias + residual + window-unpartition, fp32 out).
// EPI=3: MLP-down (bias + plain += onto fp32 out; one writer per element).
// ---------------------------------------------------------------------------
template <int EPI>
__global__ __launch_bounds__(256) void gemm_kernel(
    const unsigned short* __restrict__ A,
    const unsigned short* __restrict__ Bt,
    const float* __restrict__ bias,
    void* __restrict__ outp,
    const float* __restrict__ aux,
    int M, int K, int nbm, int nbn)
{
    __shared__ unsigned short As[2][128 * 32];
    __shared__ unsigned short Bs[2][128 * 32];
    const int tid = threadIdx.x;
    const int wave = tid >> 6, lane = tid & 63;
    const int lr = lane & 15, lq = lane >> 4;
    const int ss = (nbm + 7) >> 3;
    const int xcd = blockIdx.x & 7;
    const int s = blockIdx.x >> 3;
    const int nt = s / ss;
    const int m_loc = s - nt * ss;
    const int mt = xcd * ss + m_loc;
    if (mt >= nbm) return;
    const int m_base = mt * 128, n_base = nt * 128;
    const int wm = (wave >> 1) * 64, wn = (wave & 1) * 64;
    const int N = nbn * 128;

    const int c0 = tid, c1 = tid + 256;
    const int row0 = c0 >> 2, row1 = c1 >> 2;
    const int kc = (tid & 3) ^ ((tid >> 3) & 3);
    int ar0 = m_base + row0; ar0 = ar0 < M ? ar0 : M - 1;
    int ar1 = m_base + row1; ar1 = ar1 < M ? ar1 : M - 1;
    int br0 = n_base + row0; br0 = br0 < N ? br0 : N - 1;
    int br1 = n_base + row1; br1 = br1 < N ? br1 : N - 1;
    const unsigned short* agp0 = A + (size_t)ar0 * K + kc * 8;
    const unsigned short* agp1 = A + (size_t)ar1 * K + kc * 8;
    const unsigned short* bgp0 = Bt + (size_t)br0 * K + kc * 8;
    const unsigned short* bgp1 = Bt + (size_t)br1 * K + kc * 8;
    unsigned short* alp0 = As[0] + c0 * 8;
    unsigned short* alp1 = As[0] + c1 * 8;
    unsigned short* blp0 = Bs[0] + c0 * 8;
    unsigned short* blp1 = Bs[0] + c1 * 8;
    unsigned short* alp0b = As[1] + c0 * 8;
    unsigned short* alp1b = As[1] + c1 * 8;
    unsigned short* blp0b = Bs[1] + c0 * 8;
    unsigned short* blp1b = Bs[1] + c1 * 8;

    const int swz = (lq ^ ((lr >> 1) & 3)) * 8;

    f32x4 acc[4][4] = {};

    for (int k0 = 0; k0 < K; k0 += 64) {
        GLDS16(agp0 + k0, alp0);
        GLDS16(agp1 + k0, alp1);
        GLDS16(bgp0 + k0, blp0);
        GLDS16(bgp1 + k0, blp1);
        GLDS16(agp0 + k0 + 32, alp0b);
        GLDS16(agp1 + k0 + 32, alp1b);
        GLDS16(bgp0 + k0 + 32, blp0b);
        GLDS16(bgp1 + k0 + 32, blp1b);
        __syncthreads();
#pragma unroll
        for (int half = 0; half < 2; ++half) {
            bf16x8 af[4], bfr[4];
#pragma unroll
            for (int i = 0; i < 4; ++i) {
                af[i]  = *(const bf16x8*)(As[half] + (wm + i * 16 + lr) * 32 + swz);
                bfr[i] = *(const bf16x8*)(Bs[half] + (wn + i * 16 + lr) * 32 + swz);
            }
#pragma unroll
            for (int i = 0; i < 4; ++i)
#pragma unroll
                for (int j = 0; j < 4; ++j)
                    acc[i][j] = __builtin_amdgcn_mfma_f32_16x16x32_bf16(af[i], bfr[j], acc[i][j], 0, 0, 0);
        }
        __syncthreads();
    }

    float biasv[4];
#pragma unroll
    for (int j = 0; j < 4; ++j) biasv[j] = bias[n_base + wn + j * 16 + lr];

#pragma unroll
    for (int i = 0; i < 4; ++i) {
#pragma unroll
        for (int r = 0; r < 4; ++r) {
            const int m = m_base + wm + i * 16 + lq * 4 + r;
            if (m >= M) continue;
            int y = 0, xx = 0, b = 0;
            if constexpr (EPI == 1) {
                const int bw = m / 196, tok = m - bw * 196;
                b = bw / 25;
                const int rw = bw - b * 25;
                const int wy = rw / 5, wx = rw - wy * 5;
                const int ty = tok / 14, tx = tok - ty * 14;
                y = wy * 14 + ty; xx = wx * 14 + tx;
            }
#pragma unroll
            for (int j = 0; j < 4; ++j) {
                const int n = n_base + wn + j * 16 + lr;
                const float v = acc[i][j][r] + biasv[j];
                if constexpr (EPI == 1) {
                    if (y < 64 && xx < 64) {
                        const size_t idx = ((size_t)((b * 64 + y) * 64 + xx)) * 1024 + n;
                        ((float*)outp)[idx] = aux[idx] + v;
                    }
                } else {
                    const size_t idx = (size_t)m * 1024 + n;
                    ((float*)outp)[idx] += v;
                }
            }
        }
    }
}

// ---------------------------------------------------------------------------
// Windowed attention v3 (r8): V read DIRECTLY from global/L2 (no LDS staging
// — 26 KB/block is L2-resident; guide common-mistake #7). LDS 40.7 KB ->
// 3 blocks/CU (__launch_bounds__(256,3)): grid 800 fills in ~1.04 rounds
// (vs 1.56 at 2/CU) and 12 waves/CU hide the global-V latency.
// k>207 reads in the last ks slice run past the 208-token row into adjacent
// slot data — harmless: Pst pad cols [208,224) are zeroed, so P*V = 0.
// ---------------------------------------------------------------------------
__global__ __launch_bounds__(256, 3) void attn_kernel(
    const unsigned short* __restrict__ qkv,
    const float* __restrict__ relh, const float* __restrict__ relw,
    unsigned short* __restrict__ attn_out)
{
    __shared__ unsigned short Pst[4][16][232]; // per-wave P strip (A-layout via LDS)
    __shared__ unsigned short Db[196][28];     // rel bias: [m][0..13]=h, [14..27]=w

    const int tid = threadIdx.x;
    const int wave = tid >> 6, lane = tid & 63;
    const int lr = lane & 15, lq = lane >> 4;
    const int bw = blockIdx.x >> 4, h = blockIdx.x & 15;
    const unsigned short* qp = qkv + (size_t)((bw * 3 + 0) * 16 + h) * 13312;
    const unsigned short* kp = qkv + (size_t)((bw * 3 + 1) * 16 + h) * 13312;
    const unsigned short* vp = qkv + (size_t)((bw * 3 + 2) * 16 + h) * 13312;

    // zero this wave's Pst pad cols [208,224) once (never overwritten later)
    *(uint2*)&Pst[wave][lane >> 2][208 + (lane & 3) * 4] = make_uint2(0u, 0u);

    // rel-pos bias via MFMA: 28 tasks = (h:14 coords, w:14 coords)
    for (int t = wave; t < 28; t += 4) {
        const int isw = t >= 14;
        const int c = isw ? t - 14 : t;
        const int arow = isw ? (lr * 14 + c) : (c * 14 + lr);
        const unsigned short* ap = qp + arow * 64 + lq * 8;
        const bf16x8 a0 = *(const bf16x8*)ap;
        const bf16x8 a1 = *(const bf16x8*)(ap + 32);
        int ridx = c - lr + 13;
        ridx = ridx < 0 ? 0 : (ridx > 26 ? 26 : ridx);
        const float* tb = (isw ? relw : relh) + ridx * 64 + lq * 8;
        union BV { unsigned short u[8]; bf16x8 v; } b0, b1;
        {
            const float4 x0 = *(const float4*)tb;
            const float4 x1 = *(const float4*)(tb + 4);
            b0.u[0] = f2bf(x0.x); b0.u[1] = f2bf(x0.y); b0.u[2] = f2bf(x0.z); b0.u[3] = f2bf(x0.w);
            b0.u[4] = f2bf(x1.x); b0.u[5] = f2bf(x1.y); b0.u[6] = f2bf(x1.z); b0.u[7] = f2bf(x1.w);
            const float4 x2 = *(const float4*)(tb + 32);
            const float4 x3 = *(const float4*)(tb + 36);
            b1.u[0] = f2bf(x2.x); b1.u[1] = f2bf(x2.y); b1.u[2] = f2bf(x2.z); b1.u[3] = f2bf(x2.w);
            b1.u[4] = f2bf(x3.x); b1.u[5] = f2bf(x3.y); b1.u[6] = f2bf(x3.z); b1.u[7] = f2bf(x3.w);
        }
        f32x4 dacc = {};
        dacc = __builtin_amdgcn_mfma_f32_16x16x32_bf16(a0, b0.v, dacc, 0, 0, 0);
        dacc = __builtin_amdgcn_mfma_f32_16x16x32_bf16(a1, b1.v, dacc, 0, 0, 0);
#pragma unroll
        for (int r = 0; r < 4; ++r) {
            const int y = lq * 4 + r;
            if (y < 14 && lr < 14) {
                const int g = isw ? y * 14 + c : c * 14 + y;
                Db[g][isw ? 14 + lr : lr] = f2bf(dacc[r]);
            }
        }
    }
    __syncthreads();

    for (int mt = wave; mt < 13; mt += 4) {
        const int m0 = mt * 16;
        const unsigned short* qb = qp + (size_t)(m0 + lr) * 64 + lq * 8;
        const bf16x8 qa0 = *(const bf16x8*)qb;
        const bf16x8 qa1 = *(const bf16x8*)(qb + 32);
        f32x4 sc[13];
#pragma unroll
        for (int nt = 0; nt < 13; ++nt) {
            const unsigned short* kb = kp + (size_t)(nt * 16 + lr) * 64 + lq * 8;
            const bf16x8 k0 = *(const bf16x8*)kb;
            const bf16x8 k1 = *(const bf16x8*)(kb + 32);
            f32x4 a = {};
            a = __builtin_amdgcn_mfma_f32_16x16x32_bf16(qa0, k0, a, 0, 0, 0);
            a = __builtin_amdgcn_mfma_f32_16x16x32_bf16(qa1, k1, a, 0, 0, 0);
            sc[nt] = a;
        }
        int grow[4];
#pragma unroll
        for (int r = 0; r < 4; ++r) {
            int g = m0 + lq * 4 + r;
            grow[r] = g > 195 ? 195 : g;
        }
#pragma unroll
        for (int nt = 0; nt < 13; ++nt) {
            const int n = nt * 16 + lr;
            if (n < 196) {
                const int nx = n / 14, ny = n - nx * 14;
#pragma unroll
                for (int r = 0; r < 4; ++r)
                    sc[nt][r] = sc[nt][r] * 0.125f + bf2f(Db[grow[r]][nx]) + bf2f(Db[grow[r]][14 + ny]);
            } else {
#pragma unroll
                for (int r = 0; r < 4; ++r) sc[nt][r] = -1e30f;
            }
        }
        float rs[4];
#pragma unroll
        for (int r = 0; r < 4; ++r) {
            float mx = sc[0][r];
#pragma unroll
            for (int nt = 1; nt < 13; ++nt) mx = fmaxf(mx, sc[nt][r]);
            mx = fmaxf(mx, __shfl_xor(mx, 1));
            mx = fmaxf(mx, __shfl_xor(mx, 2));
            mx = fmaxf(mx, __shfl_xor(mx, 4));
            mx = fmaxf(mx, __shfl_xor(mx, 8));
            float s = 0.f;
#pragma unroll
            for (int nt = 0; nt < 13; ++nt) {
                const float e = __expf(sc[nt][r] - mx);
                sc[nt][r] = e;
                s += e;
            }
            s += __shfl_xor(s, 1);
            s += __shfl_xor(s, 2);
            s += __shfl_xor(s, 4);
            s += __shfl_xor(s, 8);
            rs[r] = 1.0f / s;
        }
#pragma unroll
        for (int nt = 0; nt < 13; ++nt)
#pragma unroll
            for (int r = 0; r < 4; ++r)
                Pst[wave][lq * 4 + r][nt * 16 + lr] = f2bf(sc[nt][r]);
#pragma unroll
        for (int dt = 0; dt < 4; ++dt) {
            f32x4 a = {};
#pragma unroll
            for (int ks = 0; ks < 7; ++ks) {
                const bf16x8 pa = *(const bf16x8*)&Pst[wave][lr][ks * 32 + lq * 8];
                const bf16x8 vb = *(const bf16x8*)(vp + (size_t)(dt * 16 + lr) * 208 + ks * 32 + lq * 8);
                a = __builtin_amdgcn_mfma_f32_16x16x32_bf16(pa, vb, a, 0, 0, 0);
            }
#pragma unroll
            for (int r = 0; r < 4; ++r) {
                const int m = m0 + lq * 4 + r;
                if (m < 196)
                    attn_out[(size_t)(bw * 196 + m) * 1024 + h * 64 + dt * 16 + lr] = f2bf(a[r] * rs[r]);
            }
        }
    }
}

// ---------------------------------------------------------------------------
extern "C" void kernel_launch(void* const* d_in, const int* in_sizes, int n_in,
                              void* d_out, int out_size, void* d_ws, size_t ws_size,
                              hipStream_t stream)
{
    (void)in_sizes; (void)n_in; (void)out_size; (void)ws_size;
    const float* x      = (const float*)d_in[0];
    const float* n1g    = (const float*)d_in[1];
    const float* n1b    = (const float*)d_in[2];
    const float* qkv_w  = (const float*)d_in[3];
    const float* qkv_b  = (const float*)d_in[4];
    const float* lora_a = (const float*)d_in[5];
    const float* lora_b = (const float*)d_in[6];
    const float* relh   = (const float*)d_in[7];
    const float* relw   = (const float*)d_in[8];
    const float* proj_w = (const float*)d_in[9];
    const float* proj_b = (const float*)d_in[10];
    const float* n2g    = (const float*)d_in[11];
    const float* n2b    = (const float*)d_in[12];
    const float* w1     = (const float*)d_in[13];
    const float* b1     = (const float*)d_in[14];
    const float* w2     = (const float*)d_in[15];
    const float* b2     = (const float*)d_in[16];
    float* out = (float*)d_out;

    char* ws = (char*)d_ws;
    size_t off = 0;
    auto alloc = [&](size_t bytes) {
        char* p = ws + off;
        off += (bytes + 255) & ~(size_t)255;
        return p;
    };
    unsigned short* weffT = (unsigned short*)alloc((size_t)3072 * 1024 * 2);
    unsigned short* projT = (unsigned short*)alloc((size_t)1024 * 1024 * 2);
    unsigned short* w1T   = (unsigned short*)alloc((size_t)4096 * 1024 * 2);
    unsigned short* w2T   = (unsigned short*)alloc((size_t)1024 * 4096 * 2);
    unsigned short* xnw   = (unsigned short*)alloc((size_t)9800 * 1024 * 2); // later reused as xn2
    unsigned short* qkvb  = (unsigned short*)alloc((size_t)8192 * 4096 * 2); // qkv slots / later hmid
    unsigned short* attno = (unsigned short*)alloc((size_t)9800 * 1024 * 2);

    // weight prep (bf16, transposed to NxK): weff + fused 3-way transpose
    weff_kernel<<<dim3(32, 96), 256, 0, stream>>>(qkv_w, lora_a, lora_b, weffT);
    transpose3_kernel<<<9216, 256, 0, stream>>>(proj_w, projT, w1, w1T, w2, w2T);
    // LN1 into windowed bf16 layout (pad tokens zeroed)
    ln1_kernel<<<9800, 256, 0, stream>>>(x, n1g, n1b, xnw);
    // QKV (+LoRA folded), scatter to padded slots (V pre-transposed)
    // v4: nbm=39, ss=5, nbn=12 -> grid 480
    gemm8p_v4<0><<<dim3(8 * 5 * 12), 512, 0, stream>>>(xnw, weffT, qkv_b, qkvb, 9800, 1024, 39, 12);
    // windowed attention (v3: no V staging, 3 blocks/CU)
    attn_kernel<<<800, 256, 0, stream>>>(qkvb, relh, relw, attno);
    // proj + bias + residual + unpartition -> d_out holds x1 (128-tile)
    gemm_kernel<1><<<dim3(8 * 10 * 8), 256, 0, stream>>>(attno, projT, proj_b, out, x, 9800, 1024, 77, 8);
    // LN2
    unsigned short* xn2 = xnw;
    ln2_kernel<<<8192, 256, 0, stream>>>(out, n2g, n2b, xn2);
    // MLP up (v4): nbm=32, ss=4, nbn=16 -> grid 512
    unsigned short* hmid = qkvb;
    gemm8p_v4<2><<<dim3(8 * 4 * 16), 512, 0, stream>>>(xn2, w1T, b1, hmid, 8192, 1024, 32, 16);
    // MLP down: proven 128-tile, plain += (nbm=64, ss=8, nbn=8 -> grid 512)
    gemm_kernel<3><<<dim3(8 * 8 * 8), 256, 0, stream>>>(hmid, w2T, b2, out, nullptr, 8192, 4096, 64, 8);
}

// Round 9
// 543.828 us; speedup vs baseline: 1.4478x; 1.4478x over previous
//
#include <hip/hip_runtime.h>
#include <cstdint>
#include <cstddef>

// ============================================================================
// ViT block: LN1 -> (QKV + LoRA) -> 14x14 windowed attention (decomposed
// rel-pos bias) -> proj + residual -> LN2 -> MLP (fast-tanh GELU) + residual.
//
// FINAL composition (r9 = r6, the measured optimum; every deviation retired):
//  - QKV, MLP-up: gemm8p_v4 256²/8-wave counted-vmcnt pipeline.
//    Retired: v2 drain-0 (m218-class null), v3 no-B-reuse (LDS-port-capped),
//    v5 burst-prefetch (r7: TA/TCP congestion at 1 block/CU, -12 us).
//  - proj, MLP-down: proven 128² 2-barrier m97 kernel.
//    Retired: split-K+atomicAdd (r3: 112.6, r4: 132 vs 95.9), BM=64 (r5: 109).
//  - attn: Vt LDS-staged, 4-wave, 2 blocks/CU.
//    Retired: V-from-global 3 blocks/CU (r8: 257 us, MfmaUtil 1.5% --
//    LDS staging IS the transpose/coalescing layer for the MFMA B-operand,
//    not just a bandwidth cache; common-mistake #7 does not apply here).
//  - weight prep: weff + fused transpose3 (one launch).
// qkv buffer layout: slot(bw,which,h) stride 13312 elements.
//   Q,K: [tok(208 pad)][64]   V: [64][tok(208 pad)]  (pre-transposed)
// ============================================================================

typedef __bf16 bf16x8 __attribute__((ext_vector_type(8)));
typedef float f32x4 __attribute__((ext_vector_type(4)));

__device__ __forceinline__ unsigned short f2bf(float f) {
    unsigned u = __float_as_uint(f);
    u = (u + 0x7fffu + ((u >> 16) & 1u)) >> 16;
    return (unsigned short)u;
}
__device__ __forceinline__ float bf2f(unsigned short h) {
    return __uint_as_float(((unsigned)h) << 16);
}

// async global->LDS, 16B per lane. LDS layout must be uniform_base + lane*16.
#define GLDS16(gp, lp) __builtin_amdgcn_global_load_lds( \
    (__attribute__((address_space(1))) unsigned int*)(gp), \
    (__attribute__((address_space(3))) unsigned int*)(lp), 16, 0, 0)

// ---------------------------------------------------------------------------
// Weight prep: W_effT[n][k] = qkv_w[k][n] + 2 * sum_r lora_a[k][r]*lora_b[r][n]
// ---------------------------------------------------------------------------
__global__ __launch_bounds__(256) void weff_kernel(
    const float* __restrict__ W, const float* __restrict__ la,
    const float* __restrict__ lb, unsigned short* __restrict__ Wt)
{
    __shared__ float tile[32][33];
    __shared__ float lat[32][16];
    __shared__ float lbt[16][32];
    const int kb = blockIdx.x * 32, nb = blockIdx.y * 32;
    const int tn = threadIdx.x & 31, tk = threadIdx.x >> 5;
    for (int i = threadIdx.x; i < 32 * 16; i += 256)
        lat[i >> 4][i & 15] = la[(size_t)(kb + (i >> 4)) * 16 + (i & 15)];
    for (int i = threadIdx.x; i < 16 * 32; i += 256)
        lbt[i >> 5][i & 31] = lb[(size_t)(i >> 5) * 3072 + nb + (i & 31)];
#pragma unroll
    for (int i = 0; i < 4; ++i) {
        int k = tk + i * 8;
        tile[k][tn] = W[(size_t)(kb + k) * 3072 + nb + tn];
    }
    __syncthreads();
#pragma unroll
    for (int i = 0; i < 4; ++i) {
        int n = tk + i * 8;
        float acc = tile[tn][n];
#pragma unroll
        for (int r = 0; r < 16; ++r) acc += 2.0f * lat[tn][r] * lbt[r][n];
        Wt[(size_t)(nb + n) * 1024 + kb + tn] = f2bf(acc);
    }
}

// ---------------------------------------------------------------------------
// Fused 3-way transpose: fp32 (KxN) -> bf16 (NxK) for proj_w / w1 / w2.
// ---------------------------------------------------------------------------
__global__ __launch_bounds__(256) void transpose3_kernel(
    const float* __restrict__ Wp, unsigned short* __restrict__ WpT,
    const float* __restrict__ W1, unsigned short* __restrict__ W1T,
    const float* __restrict__ W2, unsigned short* __restrict__ W2T)
{
    __shared__ float tile[32][33];
    const int id = blockIdx.x;
    const float* W; unsigned short* Wt; int Kdim, Ndim, kb, nb;
    if (id < 1024)      { W = Wp; Wt = WpT; Kdim = 1024; Ndim = 1024; const int t = id;        kb = t >> 5; nb = t & 31; }
    else if (id < 5120) { W = W1; Wt = W1T; Kdim = 1024; Ndim = 4096; const int t = id - 1024; kb = t >> 7; nb = t & 127; }
    else                { W = W2; Wt = W2T; Kdim = 4096; Ndim = 1024; const int t = id - 5120; kb = t >> 5; nb = t & 31; }
    kb <<= 5; nb <<= 5;
    const int tn = threadIdx.x & 31, tk = threadIdx.x >> 5;
#pragma unroll
    for (int i = 0; i < 4; ++i) {
        int k = tk + i * 8;
        tile[k][tn] = W[(size_t)(kb + k) * Ndim + nb + tn];
    }
    __syncthreads();
#pragma unroll
    for (int i = 0; i < 4; ++i) {
        int n = tk + i * 8;
        Wt[(size_t)(nb + n) * Kdim + kb + tn] = f2bf(tile[tn][n]);
    }
}

// ---------------------------------------------------------------------------
// LN1: x (2,64,64,1024) fp32 -> windowed bf16 (50*196, 1024); pad tokens = 0.
// ---------------------------------------------------------------------------
__global__ __launch_bounds__(256) void ln1_kernel(
    const float* __restrict__ x, const float* __restrict__ g,
    const float* __restrict__ b, unsigned short* __restrict__ out)
{
    const int blk = blockIdx.x;             // 0..9799
    const int tid = threadIdx.x;
    const int bw = blk / 196, tok = blk - bw * 196;
    const int bat = bw / 25, rw = bw - bat * 25;
    const int wy = rw / 5, wx = rw - wy * 5;
    const int ty = tok / 14, tx = tok - ty * 14;
    const int y = wy * 14 + ty, xx = wx * 14 + tx;
    unsigned short* orow = out + (size_t)blk * 1024;
    if (y >= 64 || xx >= 64) {
        *(uint2*)(orow + tid * 4) = make_uint2(0u, 0u);
        return;
    }
    const float* irow = x + ((size_t)((bat * 64 + y) * 64 + xx)) * 1024;
    const float4 v = *(const float4*)(irow + tid * 4);
    float s = v.x + v.y + v.z + v.w;
    float ss = v.x * v.x + v.y * v.y + v.z * v.z + v.w * v.w;
    for (int o = 32; o > 0; o >>= 1) { s += __shfl_xor(s, o); ss += __shfl_xor(ss, o); }
    __shared__ float red[8];
    const int wave = tid >> 6, lane = tid & 63;
    if (lane == 0) { red[wave] = s; red[4 + wave] = ss; }
    __syncthreads();
    s = red[0] + red[1] + red[2] + red[3];
    ss = red[4] + red[5] + red[6] + red[7];
    const float mu = s * (1.0f / 1024.0f);
    const float var = ss * (1.0f / 1024.0f) - mu * mu;
    const float rstd = rsqrtf(var + 1e-6f);
    const float4 gv = *(const float4*)(g + tid * 4);
    const float4 bv = *(const float4*)(b + tid * 4);
    const float a0 = (v.x - mu) * rstd * gv.x + bv.x;
    const float a1 = (v.y - mu) * rstd * gv.y + bv.y;
    const float a2 = (v.z - mu) * rstd * gv.z + bv.z;
    const float a3 = (v.w - mu) * rstd * gv.w + bv.w;
    const unsigned r0 = (unsigned)f2bf(a0) | ((unsigned)f2bf(a1) << 16);
    const unsigned r1 = (unsigned)f2bf(a2) | ((unsigned)f2bf(a3) << 16);
    *(uint2*)(orow + tid * 4) = make_uint2(r0, r1);
}

// LN2: rows of x1 (d_out, fp32) -> bf16, 8192 rows
__global__ __launch_bounds__(256) void ln2_kernel(
    const float* __restrict__ x, const float* __restrict__ g,
    const float* __restrict__ b, unsigned short* __restrict__ out)
{
    const int blk = blockIdx.x;
    const int tid = threadIdx.x;
    const float* irow = x + (size_t)blk * 1024;
    unsigned short* orow = out + (size_t)blk * 1024;
    const float4 v = *(const float4*)(irow + tid * 4);
    float s = v.x + v.y + v.z + v.w;
    float ss = v.x * v.x + v.y * v.y + v.z * v.z + v.w * v.w;
    for (int o = 32; o > 0; o >>= 1) { s += __shfl_xor(s, o); ss += __shfl_xor(ss, o); }
    __shared__ float red[8];
    const int wave = tid >> 6, lane = tid & 63;
    if (lane == 0) { red[wave] = s; red[4 + wave] = ss; }
    __syncthreads();
    s = red[0] + red[1] + red[2] + red[3];
    ss = red[4] + red[5] + red[6] + red[7];
    const float mu = s * (1.0f / 1024.0f);
    const float var = ss * (1.0f / 1024.0f) - mu * mu;
    const float rstd = rsqrtf(var + 1e-6f);
    const float4 gv = *(const float4*)(g + tid * 4);
    const float4 bv = *(const float4*)(b + tid * 4);
    const float a0 = (v.x - mu) * rstd * gv.x + bv.x;
    const float a1 = (v.y - mu) * rstd * gv.y + bv.y;
    const float a2 = (v.z - mu) * rstd * gv.z + bv.z;
    const float a3 = (v.w - mu) * rstd * gv.w + bv.w;
    const unsigned r0 = (unsigned)f2bf(a0) | ((unsigned)f2bf(a1) << 16);
    const unsigned r1 = (unsigned)f2bf(a2) | ((unsigned)f2bf(a3) << 16);
    *(uint2*)(orow + tid * 4) = make_uint2(r0, r1);
}

// ---------------------------------------------------------------------------
// gemm8p_v4: C[m][n] = sum_k A[m][k] * Bt[n][k]; BM=BN=256, BK=64, 512 thr.
// 4 phases/K-tile with B-register reuse (reads 8/4/8/4), counted vmcnt(2)
// mid+boundary, stage order {B01|B23|A02|A13}; LDS slot = chunk^(row&7)
// (0 conflicts, verified r3); inverse swizzle on per-lane global source.
// ---------------------------------------------------------------------------
template <int EPI>
__global__ __launch_bounds__(512, 2) void gemm8p_v4(
    const unsigned short* __restrict__ A,
    const unsigned short* __restrict__ Bt,
    const float* __restrict__ bias,
    void* __restrict__ outp,
    int M, int K, int nbm, int nbn)
{
    __shared__ unsigned short As_s[2 * 16384];
    __shared__ unsigned short Bs_s[2 * 16384];

    const int tid = threadIdx.x;
    const int wave = tid >> 6, lane = tid & 63;
    const int lr = lane & 15, lq = lane >> 4;

    const int ss = (nbm + 7) >> 3;
    const int xcd = blockIdx.x & 7;
    const int sidx = blockIdx.x >> 3;
    const int ntl = sidx / ss;
    const int m_loc = sidx - ntl * ss;
    const int mt = xcd * ss + m_loc;
    if (mt >= nbm) return;
    const int m_base = mt * 256, n_base = ntl * 256;
    const int NT = K >> 6;

    const int wm = (wave >> 2) * 128;           // 2 m-groups
    const int wn = (wave & 3) * 64;             // 4 n-groups

    // --- staging pointers: thread covers (row u*64 + tid>>3, slot tid&7) ---
    const int srow = tid >> 3, sslot = tid & 7;
    const int gch = sslot ^ (srow & 7);          // inverse swizzle on source
    const unsigned short* a_gp[4];
    const unsigned short* b_gp[4];
#pragma unroll
    for (int u = 0; u < 4; ++u) {
        int ar = m_base + u * 64 + srow; ar = ar < M ? ar : M - 1;
        a_gp[u] = A + (size_t)ar * K + gch * 8;
        b_gp[u] = Bt + (size_t)(n_base + u * 64 + srow) * K + gch * 8;
    }
#define STG_A(t, u) GLDS16(a_gp[u] + (size_t)(t) * 64, As_s + (((t) & 1) << 14) + (u) * 4096 + tid * 8)
#define STG_B(t, u) GLDS16(b_gp[u] + (size_t)(t) * 64, Bs_s + (((t) & 1) << 14) + (u) * 4096 + tid * 8)

    // --- fragment read offsets (shorts): row*64 + slot*8, slot = chunk^(lr&7)
    const int sl0 = lq ^ (lr & 7);               // kh0 slot; kh1 = sl0 ^ 4
    const int a_off = (wm + lr) * 64 + sl0 * 8;  // ^32 toggles k-half
    const int b_off = (wn + lr) * 64 + sl0 * 8;

    f32x4 acc[8][4] = {};

    // --- prologue: tile 0, {B all, A-u0,u2} first, then A-u1,u3 ---
    STG_B(0, 0); STG_B(0, 1); STG_B(0, 2); STG_B(0, 3);
    STG_A(0, 0); STG_A(0, 2);
    STG_A(0, 1); STG_A(0, 3);
    asm volatile("s_waitcnt vmcnt(2)" ::: "memory");
    __builtin_amdgcn_s_barrier();

    for (int t = 0; t < NT; ++t) {
        const unsigned short* Ab = As_s + ((t & 1) << 14);
        const unsigned short* Bb = Bs_s + ((t & 1) << 14);
        bf16x8 af[4], bfv[4];
        // ---- ph0: af[0..3] + bf, kh0; stage B-u0,u1(t+1); mid vmcnt ----
#pragma unroll
        for (int mf = 0; mf < 4; ++mf) af[mf] = *(const bf16x8*)(Ab + a_off + mf * 1024);
#pragma unroll
        for (int nf = 0; nf < 4; ++nf) bfv[nf] = *(const bf16x8*)(Bb + b_off + nf * 1024);
        if (t + 1 < NT) { STG_B(t + 1, 0); STG_B(t + 1, 1); }
        __builtin_amdgcn_s_barrier();
        asm volatile("s_waitcnt lgkmcnt(0)" ::: "memory");
        __builtin_amdgcn_sched_barrier(0);
        __builtin_amdgcn_s_setprio(1);
#pragma unroll
        for (int mf = 0; mf < 4; ++mf)
#pragma unroll
            for (int nf = 0; nf < 4; ++nf)
                acc[mf][nf] = __builtin_amdgcn_mfma_f32_16x16x32_bf16(af[mf], bfv[nf], acc[mf][nf], 0, 0, 0);
        __builtin_amdgcn_s_setprio(0);
        if (t == NT - 1) { asm volatile("s_waitcnt vmcnt(0)" ::: "memory"); }
        else             { asm volatile("s_waitcnt vmcnt(2)" ::: "memory"); }
        __builtin_amdgcn_s_barrier();
        // ---- ph1: af[4..7] kh0 (bfv reused); stage B-u2,u3(t+1) ----
#pragma unroll
        for (int mf = 0; mf < 4; ++mf) af[mf] = *(const bf16x8*)(Ab + a_off + (4 + mf) * 1024);
        if (t + 1 < NT) { STG_B(t + 1, 2); STG_B(t + 1, 3); }
        __builtin_amdgcn_s_barrier();
        asm volatile("s_waitcnt lgkmcnt(0)" ::: "memory");
        __builtin_amdgcn_sched_barrier(0);
        __builtin_amdgcn_s_setprio(1);
#pragma unroll
        for (int mf = 0; mf < 4; ++mf)
#pragma unroll
            for (int nf = 0; nf < 4; ++nf)
                acc[4 + mf][nf] = __builtin_amdgcn_mfma_f32_16x16x32_bf16(af[mf], bfv[nf], acc[4 + mf][nf], 0, 0, 0);
        __builtin_amdgcn_s_setprio(0);
        __builtin_amdgcn_s_barrier();
        // ---- ph2: af[0..3] + bf, kh1; stage A-u0,u2(t+1) ----
#pragma unroll
        for (int mf = 0; mf < 4; ++mf) af[mf] = *(const bf16x8*)(Ab + (a_off ^ 32) + mf * 1024);
#pragma unroll
        for (int nf = 0; nf < 4; ++nf) bfv[nf] = *(const bf16x8*)(Bb + (b_off ^ 32) + nf * 1024);
        if (t + 1 < NT) { STG_A(t + 1, 0); STG_A(t + 1, 2); }
        __builtin_amdgcn_s_barrier();
        asm volatile("s_waitcnt lgkmcnt(0)" ::: "memory");
        __builtin_amdgcn_sched_barrier(0);
        __builtin_amdgcn_s_setprio(1);
#pragma unroll
        for (int mf = 0; mf < 4; ++mf)
#pragma unroll
            for (int nf = 0; nf < 4; ++nf)
                acc[mf][nf] = __builtin_amdgcn_mfma_f32_16x16x32_bf16(af[mf], bfv[nf], acc[mf][nf], 0, 0, 0);
        __builtin_amdgcn_s_setprio(0);
        __builtin_amdgcn_s_barrier();
        // ---- ph3: af[4..7] kh1 (bfv reused); stage A-u1,u3(t+1); bnd vmcnt ----
#pragma unroll
        for (int mf = 0; mf < 4; ++mf) af[mf] = *(const bf16x8*)(Ab + (a_off ^ 32) + (4 + mf) * 1024);
        if (t + 1 < NT) { STG_A(t + 1, 1); STG_A(t + 1, 3); }
        __builtin_amdgcn_s_barrier();
        asm volatile("s_waitcnt lgkmcnt(0)" ::: "memory");
        __builtin_amdgcn_sched_barrier(0);
        __builtin_amdgcn_s_setprio(1);
#pragma unroll
        for (int mf = 0; mf < 4; ++mf)
#pragma unroll
            for (int nf = 0; nf < 4; ++nf)
                acc[4 + mf][nf] = __builtin_amdgcn_mfma_f32_16x16x32_bf16(af[mf], bfv[nf], acc[4 + mf][nf], 0, 0, 0);
        __builtin_amdgcn_s_setprio(0);
        if (t < NT - 1) { asm volatile("s_waitcnt vmcnt(2)" ::: "memory"); }
        __builtin_amdgcn_s_barrier();
    }
#undef STG_A
#undef STG_B

    // ------------------------------- epilogue -------------------------------
    float biasv[4];
#pragma unroll
    for (int j = 0; j < 4; ++j) biasv[j] = bias[n_base + wn + j * 16 + lr];

    if constexpr (EPI == 0) {
        // qkv scatter; V written transposed, packed 4 tokens (8B) per store.
        // 196 % 4 == 0 and row-starts % 4 == 0 -> 4-row chunk never straddles.
#pragma unroll
        for (int i = 0; i < 8; ++i) {
            const int m0i = m_base + wm + i * 16 + lq * 4;
            if (m0i >= M) continue;
            const int bw = m0i / 196, tok0 = m0i - bw * 196;
#pragma unroll
            for (int j = 0; j < 4; ++j) {
                const int n = n_base + wn + j * 16 + lr;
                const int which = n >> 10, hh = (n >> 6) & 15, d = n & 63;
                unsigned short* slotp = (unsigned short*)outp + (size_t)((bw * 3 + which) * 16 + hh) * 13312;
                if (which == 2) {
                    unsigned long long pv = 0;
#pragma unroll
                    for (int r = 0; r < 4; ++r)
                        pv |= (unsigned long long)f2bf(acc[i][j][r] + biasv[j]) << (16 * r);
                    *(unsigned long long*)(slotp + (size_t)d * 208 + tok0) = pv;
                } else {
#pragma unroll
                    for (int r = 0; r < 4; ++r)
                        slotp[(size_t)(tok0 + r) * 64 + d] = f2bf(acc[i][j][r] + biasv[j]);
                }
            }
        }
    } else {
        // EPI == 2: fast tanh-GELU -> bf16 [M][4096]
#pragma unroll
        for (int i = 0; i < 8; ++i) {
#pragma unroll
            for (int r = 0; r < 4; ++r) {
                const int m = m_base + wm + i * 16 + lq * 4 + r;
                if (m >= M) continue;
#pragma unroll
                for (int j = 0; j < 4; ++j) {
                    const int n = n_base + wn + j * 16 + lr;
                    const float v = acc[i][j][r] + biasv[j];
                    const float t2 = 1.5957691216f * (v + 0.044715f * v * v * v);
                    const float e = __expf(-t2);
                    const float gl = v * __builtin_amdgcn_rcpf(1.0f + e);
                    ((unsigned short*)outp)[(size_t)m * 4096 + n] = f2bf(gl);
                }
            }
        }
    }
}

// ---------------------------------------------------------------------------
// Proven 128-tile 2-barrier GEMM (m97 structure) — proj and MLP-down.
// EPI=1: proj (bias + residual + window-unpartition, fp32 out).
// EPI=3: MLP-down (bias + plain += onto fp32 out; one writer per element).
// ---------------------------------------------------------------------------
template <int EPI>
__global__ __launch_bounds__(256) void gemm_kernel(
    const unsigned short* __restrict__ A,
    const unsigned short* __restrict__ Bt,
    const float* __restrict__ bias,
    void* __restrict__ outp,
    const float* __restrict__ aux,
    int M, int K, int nbm, int nbn)
{
    __shared__ unsigned short As[2][128 * 32];
    __shared__ unsigned short Bs[2][128 * 32];
    const int tid = threadIdx.x;
    const int wave = tid >> 6, lane = tid & 63;
    const int lr = lane & 15, lq = lane >> 4;
    const int ss = (nbm + 7) >> 3;
    const int xcd = blockIdx.x & 7;
    const int s = blockIdx.x >> 3;
    const int nt = s / ss;
    const int m_loc = s - nt * ss;
    const int mt = xcd * ss + m_loc;
    if (mt >= nbm) return;
    const int m_base = mt * 128, n_base = nt * 128;
    const int wm = (wave >> 1) * 64, wn = (wave & 1) * 64;
    const int N = nbn * 128;

    const int c0 = tid, c1 = tid + 256;
    const int row0 = c0 >> 2, row1 = c1 >> 2;
    const int kc = (tid & 3) ^ ((tid >> 3) & 3);
    int ar0 = m_base + row0; ar0 = ar0 < M ? ar0 : M - 1;
    int ar1 = m_base + row1; ar1 = ar1 < M ? ar1 : M - 1;
    int br0 = n_base + row0; br0 = br0 < N ? br0 : N - 1;
    int br1 = n_base + row1; br1 = br1 < N ? br1 : N - 1;
    const unsigned short* agp0 = A + (size_t)ar0 * K + kc * 8;
    const unsigned short* agp1 = A + (size_t)ar1 * K + kc * 8;
    const unsigned short* bgp0 = Bt + (size_t)br0 * K + kc * 8;
    const unsigned short* bgp1 = Bt + (size_t)br1 * K + kc * 8;
    unsigned short* alp0 = As[0] + c0 * 8;
    unsigned short* alp1 = As[0] + c1 * 8;
    unsigned short* blp0 = Bs[0] + c0 * 8;
    unsigned short* blp1 = Bs[0] + c1 * 8;
    unsigned short* alp0b = As[1] + c0 * 8;
    unsigned short* alp1b = As[1] + c1 * 8;
    unsigned short* blp0b = Bs[1] + c0 * 8;
    unsigned short* blp1b = Bs[1] + c1 * 8;

    const int swz = (lq ^ ((lr >> 1) & 3)) * 8;

    f32x4 acc[4][4] = {};

    for (int k0 = 0; k0 < K; k0 += 64) {
        GLDS16(agp0 + k0, alp0);
        GLDS16(agp1 + k0, alp1);
        GLDS16(bgp0 + k0, blp0);
        GLDS16(bgp1 + k0, blp1);
        GLDS16(agp0 + k0 + 32, alp0b);
        GLDS16(agp1 + k0 + 32, alp1b);
        GLDS16(bgp0 + k0 + 32, blp0b);
        GLDS16(bgp1 + k0 + 32, blp1b);
        __syncthreads();
#pragma unroll
        for (int half = 0; half < 2; ++half) {
            bf16x8 af[4], bfr[4];
#pragma unroll
            for (int i = 0; i < 4; ++i) {
                af[i]  = *(const bf16x8*)(As[half] + (wm + i * 16 + lr) * 32 + swz);
                bfr[i] = *(const bf16x8*)(Bs[half] + (wn + i * 16 + lr) * 32 + swz);
            }
#pragma unroll
            for (int i = 0; i < 4; ++i)
#pragma unroll
                for (int j = 0; j < 4; ++j)
                    acc[i][j] = __builtin_amdgcn_mfma_f32_16x16x32_bf16(af[i], bfr[j], acc[i][j], 0, 0, 0);
        }
        __syncthreads();
    }

    float biasv[4];
#pragma unroll
    for (int j = 0; j < 4; ++j) biasv[j] = bias[n_base + wn + j * 16 + lr];

#pragma unroll
    for (int i = 0; i < 4; ++i) {
#pragma unroll
        for (int r = 0; r < 4; ++r) {
            const int m = m_base + wm + i * 16 + lq * 4 + r;
            if (m >= M) continue;
            int y = 0, xx = 0, b = 0;
            if constexpr (EPI == 1) {
                const int bw = m / 196, tok = m - bw * 196;
                b = bw / 25;
                const int rw = bw - b * 25;
                const int wy = rw / 5, wx = rw - wy * 5;
                const int ty = tok / 14, tx = tok - ty * 14;
                y = wy * 14 + ty; xx = wx * 14 + tx;
            }
#pragma unroll
            for (int j = 0; j < 4; ++j) {
                const int n = n_base + wn + j * 16 + lr;
                const float v = acc[i][j][r] + biasv[j];
                if constexpr (EPI == 1) {
                    if (y < 64 && xx < 64) {
                        const size_t idx = ((size_t)((b * 64 + y) * 64 + xx)) * 1024 + n;
                        ((float*)outp)[idx] = aux[idx] + v;
                    }
                } else {
                    const size_t idx = (size_t)m * 1024 + n;
                    ((float*)outp)[idx] += v;
                }
            }
        }
    }
}

// ---------------------------------------------------------------------------
// Windowed attention v2 (r6 proven). Grid = 800 (window*head), 256 threads /
// 4 waves, 2 blocks/CU (LDS 70.4 KB). Vt LDS staging retained: it is the
// transpose/coalescing layer for the PV MFMA B-operand (r8 showed direct
// global V reads collapse MfmaUtil to 1.5%).
// ---------------------------------------------------------------------------
__global__ __launch_bounds__(256, 2) void attn_kernel(
    const unsigned short* __restrict__ qkv,
    const float* __restrict__ relh, const float* __restrict__ relw,
    unsigned short* __restrict__ attn_out)
{
    __shared__ unsigned short Vt[64][232];     // V^T staged (cols 0..231 from global)
    __shared__ unsigned short Pst[4][16][232]; // per-wave P strip (A-layout via LDS)
    __shared__ unsigned short Db[196][28];     // rel bias: [m][0..13]=h, [14..27]=w

    const int tid = threadIdx.x;
    const int wave = tid >> 6, lane = tid & 63;
    const int lr = lane & 15, lq = lane >> 4;
    const int bw = blockIdx.x >> 4, h = blockIdx.x & 15;
    const unsigned short* qp = qkv + (size_t)((bw * 3 + 0) * 16 + h) * 13312;
    const unsigned short* kp = qkv + (size_t)((bw * 3 + 1) * 16 + h) * 13312;
    const unsigned short* vp = qkv + (size_t)((bw * 3 + 2) * 16 + h) * 13312;

    // zero this wave's Pst pad cols [208,224) once (never overwritten later)
    *(uint2*)&Pst[wave][lane >> 2][208 + (lane & 3) * 4] = make_uint2(0u, 0u);

    // stage V^T: 64 rows x 232 cols (29 x 16B chunks per row) async from global
    {
        unsigned short* vtf = &Vt[0][0];
        for (int idx = tid; idx < 64 * 29; idx += 256) {
            const int d = idx / 29, c = idx - d * 29;
            GLDS16(vp + d * 208 + c * 8, vtf + idx * 8);
        }
    }

    // rel-pos bias via MFMA: 28 tasks = (h:14 coords, w:14 coords)
    for (int t = wave; t < 28; t += 4) {
        const int isw = t >= 14;
        const int c = isw ? t - 14 : t;
        const int arow = isw ? (lr * 14 + c) : (c * 14 + lr);
        const unsigned short* ap = qp + arow * 64 + lq * 8;
        const bf16x8 a0 = *(const bf16x8*)ap;
        const bf16x8 a1 = *(const bf16x8*)(ap + 32);
        int ridx = c - lr + 13;
        ridx = ridx < 0 ? 0 : (ridx > 26 ? 26 : ridx);
        const float* tb = (isw ? relw : relh) + ridx * 64 + lq * 8;
        union BV { unsigned short u[8]; bf16x8 v; } b0, b1;
        {
            const float4 x0 = *(const float4*)tb;
            const float4 x1 = *(const float4*)(tb + 4);
            b0.u[0] = f2bf(x0.x); b0.u[1] = f2bf(x0.y); b0.u[2] = f2bf(x0.z); b0.u[3] = f2bf(x0.w);
            b0.u[4] = f2bf(x1.x); b0.u[5] = f2bf(x1.y); b0.u[6] = f2bf(x1.z); b0.u[7] = f2bf(x1.w);
            const float4 x2 = *(const float4*)(tb + 32);
            const float4 x3 = *(const float4*)(tb + 36);
            b1.u[0] = f2bf(x2.x); b1.u[1] = f2bf(x2.y); b1.u[2] = f2bf(x2.z); b1.u[3] = f2bf(x2.w);
            b1.u[4] = f2bf(x3.x); b1.u[5] = f2bf(x3.y); b1.u[6] = f2bf(x3.z); b1.u[7] = f2bf(x3.w);
        }
        f32x4 dacc = {};
        dacc = __builtin_amdgcn_mfma_f32_16x16x32_bf16(a0, b0.v, dacc, 0, 0, 0);
        dacc = __builtin_amdgcn_mfma_f32_16x16x32_bf16(a1, b1.v, dacc, 0, 0, 0);
#pragma unroll
        for (int r = 0; r < 4; ++r) {
            const int y = lq * 4 + r;
            if (y < 14 && lr < 14) {
                const int g = isw ? y * 14 + c : c * 14 + y;
                Db[g][isw ? 14 + lr : lr] = f2bf(dacc[r]);
            }
        }
    }
    __syncthreads();

    for (int mt = wave; mt < 13; mt += 4) {
        const int m0 = mt * 16;
        const unsigned short* qb = qp + (size_t)(m0 + lr) * 64 + lq * 8;
        const bf16x8 qa0 = *(const bf16x8*)qb;
        const bf16x8 qa1 = *(const bf16x8*)(qb + 32);
        f32x4 sc[13];
#pragma unroll
        for (int nt = 0; nt < 13; ++nt) {
            const unsigned short* kb = kp + (size_t)(nt * 16 + lr) * 64 + lq * 8;
            const bf16x8 k0 = *(const bf16x8*)kb;
            const bf16x8 k1 = *(const bf16x8*)(kb + 32);
            f32x4 a = {};
            a = __builtin_amdgcn_mfma_f32_16x16x32_bf16(qa0, k0, a, 0, 0, 0);
            a = __builtin_amdgcn_mfma_f32_16x16x32_bf16(qa1, k1, a, 0, 0, 0);
            sc[nt] = a;
        }
        int grow[4];
#pragma unroll
        for (int r = 0; r < 4; ++r) {
            int g = m0 + lq * 4 + r;
            grow[r] = g > 195 ? 195 : g;
        }
#pragma unroll
        for (int nt = 0; nt < 13; ++nt) {
            const int n = nt * 16 + lr;
            if (n < 196) {
                const int nx = n / 14, ny = n - nx * 14;
#pragma unroll
                for (int r = 0; r < 4; ++r)
                    sc[nt][r] = sc[nt][r] * 0.125f + bf2f(Db[grow[r]][nx]) + bf2f(Db[grow[r]][14 + ny]);
            } else {
#pragma unroll
                for (int r = 0; r < 4; ++r) sc[nt][r] = -1e30f;
            }
        }
        float rs[4];
#pragma unroll
        for (int r = 0; r < 4; ++r) {
            float mx = sc[0][r];
#pragma unroll
            for (int nt = 1; nt < 13; ++nt) mx = fmaxf(mx, sc[nt][r]);
            mx = fmaxf(mx, __shfl_xor(mx, 1));
            mx = fmaxf(mx, __shfl_xor(mx, 2));
            mx = fmaxf(mx, __shfl_xor(mx, 4));
            mx = fmaxf(mx, __shfl_xor(mx, 8));
            float s = 0.f;
#pragma unroll
            for (int nt = 0; nt < 13; ++nt) {
                const float e = __expf(sc[nt][r] - mx);
                sc[nt][r] = e;
                s += e;
            }
            s += __shfl_xor(s, 1);
            s += __shfl_xor(s, 2);
            s += __shfl_xor(s, 4);
            s += __shfl_xor(s, 8);
            rs[r] = 1.0f / s;
        }
#pragma unroll
        for (int nt = 0; nt < 13; ++nt)
#pragma unroll
            for (int r = 0; r < 4; ++r)
                Pst[wave][lq * 4 + r][nt * 16 + lr] = f2bf(sc[nt][r]);
#pragma unroll
        for (int dt = 0; dt < 4; ++dt) {
            f32x4 a = {};
#pragma unroll
            for (int ks = 0; ks < 7; ++ks) {
                const bf16x8 pa = *(const bf16x8*)&Pst[wave][lr][ks * 32 + lq * 8];
                const bf16x8 vb = *(const bf16x8*)&Vt[dt * 16 + lr][ks * 32 + lq * 8];
                a = __builtin_amdgcn_mfma_f32_16x16x32_bf16(pa, vb, a, 0, 0, 0);
            }
#pragma unroll
            for (int r = 0; r < 4; ++r) {
                const int m = m0 + lq * 4 + r;
                if (m < 196)
                    attn_out[(size_t)(bw * 196 + m) * 1024 + h * 64 + dt * 16 + lr] = f2bf(a[r] * rs[r]);
            }
        }
    }
}

// ---------------------------------------------------------------------------
extern "C" void kernel_launch(void* const* d_in, const int* in_sizes, int n_in,
                              void* d_out, int out_size, void* d_ws, size_t ws_size,
                              hipStream_t stream)
{
    (void)in_sizes; (void)n_in; (void)out_size; (void)ws_size;
    const float* x      = (const float*)d_in[0];
    const float* n1g    = (const float*)d_in[1];
    const float* n1b    = (const float*)d_in[2];
    const float* qkv_w  = (const float*)d_in[3];
    const float* qkv_b  = (const float*)d_in[4];
    const float* lora_a = (const float*)d_in[5];
    const float* lora_b = (const float*)d_in[6];
    const float* relh   = (const float*)d_in[7];
    const float* relw   = (const float*)d_in[8];
    const float* proj_w = (const float*)d_in[9];
    const float* proj_b = (const float*)d_in[10];
    const float* n2g    = (const float*)d_in[11];
    const float* n2b    = (const float*)d_in[12];
    const float* w1     = (const float*)d_in[13];
    const float* b1     = (const float*)d_in[14];
    const float* w2     = (const float*)d_in[15];
    const float* b2     = (const float*)d_in[16];
    float* out = (float*)d_out;

    char* ws = (char*)d_ws;
    size_t off = 0;
    auto alloc = [&](size_t bytes) {
        char* p = ws + off;
        off += (bytes + 255) & ~(size_t)255;
        return p;
    };
    unsigned short* weffT = (unsigned short*)alloc((size_t)3072 * 1024 * 2);
    unsigned short* projT = (unsigned short*)alloc((size_t)1024 * 1024 * 2);
    unsigned short* w1T   = (unsigned short*)alloc((size_t)4096 * 1024 * 2);
    unsigned short* w2T   = (unsigned short*)alloc((size_t)1024 * 4096 * 2);
    unsigned short* xnw   = (unsigned short*)alloc((size_t)9800 * 1024 * 2); // later reused as xn2
    unsigned short* qkvb  = (unsigned short*)alloc((size_t)8192 * 4096 * 2); // qkv slots / later hmid
    unsigned short* attno = (unsigned short*)alloc((size_t)9800 * 1024 * 2);

    // weight prep (bf16, transposed to NxK): weff + fused 3-way transpose
    weff_kernel<<<dim3(32, 96), 256, 0, stream>>>(qkv_w, lora_a, lora_b, weffT);
    transpose3_kernel<<<9216, 256, 0, stream>>>(proj_w, projT, w1, w1T, w2, w2T);
    // LN1 into windowed bf16 layout (pad tokens zeroed)
    ln1_kernel<<<9800, 256, 0, stream>>>(x, n1g, n1b, xnw);
    // QKV (+LoRA folded), scatter to padded slots (V pre-transposed)
    // v4: nbm=39, ss=5, nbn=12 -> grid 480
    gemm8p_v4<0><<<dim3(8 * 5 * 12), 512, 0, stream>>>(xnw, weffT, qkv_b, qkvb, 9800, 1024, 39, 12);
    // windowed attention (Vt staged, 2 blocks/CU — proven)
    attn_kernel<<<800, 256, 0, stream>>>(qkvb, relh, relw, attno);
    // proj + bias + residual + unpartition -> d_out holds x1 (128-tile)
    gemm_kernel<1><<<dim3(8 * 10 * 8), 256, 0, stream>>>(attno, projT, proj_b, out, x, 9800, 1024, 77, 8);
    // LN2
    unsigned short* xn2 = xnw;
    ln2_kernel<<<8192, 256, 0, stream>>>(out, n2g, n2b, xn2);
    // MLP up (v4): nbm=32, ss=4, nbn=16 -> grid 512
    unsigned short* hmid = qkvb;
    gemm8p_v4<2><<<dim3(8 * 4 * 16), 512, 0, stream>>>(xn2, w1T, b1, hmid, 8192, 1024, 32, 16);
    // MLP down: proven 128-tile, plain += (nbm=64, ss=8, nbn=8 -> grid 512)
    gemm_kernel<3><<<dim3(8 * 8 * 8), 256, 0, stream>>>(hmid, w2T, b2, out, nullptr, 8192, 4096, 64, 8);
}

// Round 10
// 534.780 us; speedup vs baseline: 1.4723x; 1.0169x over previous
//
#include <hip/hip_runtime.h>
#include <cstdint>
#include <cstddef>

// ============================================================================
// ViT block: LN1 -> (QKV + LoRA) -> 14x14 windowed attention (decomposed
// rel-pos bias) -> proj + residual -> LN2 -> MLP (fast-tanh GELU) + residual.
//
// Composition (r10):
//  - QKV, MLP-up: gemm8p_v4 256²/8-wave counted-vmcnt pipeline (best, r6).
//  - proj: proven 128² 2-barrier m97 kernel (unchanged).
//  - MLP-down (r10 experiment): gemm_db_kernel = 128² tile with CROSS-K-TILE
//    double-buffer + counted vmcnt(8): stage tile t+1 at top of iter t into
//    the other 32KB buffer pair, wait vmcnt(8) (retires tile t, leaves t+1 in
//    flight), RAW s_barrier (NOT __syncthreads -- that drains vmcnt(0)),
//    compute, barrier. Gives each K-tile's loads a full compute phase of
//    latency cover on top of 2-block/CU TLP (m103's 912 TF was at 4/CU; our
//    695 TF at 2/CU is the TLP deficit this targets). LDS 64KB, still 2/CU.
//  - attn: Vt LDS-staged (r8 proved staging IS the MFMA-operand transpose
//    layer, not a bandwidth cache).
//  - weight prep: weff + fused transpose3.
// Retired by measurement: split-K+atomics (r3/r4), BM=64 (r5), 256² for
// N=1024 shapes (r3), v5 burst-prefetch (r7), V-from-global attn (r8).
// qkv buffer layout: slot(bw,which,h) stride 13312 elements.
//   Q,K: [tok(208 pad)][64]   V: [64][tok(208 pad)]  (pre-transposed)
// ============================================================================

typedef __bf16 bf16x8 __attribute__((ext_vector_type(8)));
typedef float f32x4 __attribute__((ext_vector_type(4)));

__device__ __forceinline__ unsigned short f2bf(float f) {
    unsigned u = __float_as_uint(f);
    u = (u + 0x7fffu + ((u >> 16) & 1u)) >> 16;
    return (unsigned short)u;
}
__device__ __forceinline__ float bf2f(unsigned short h) {
    return __uint_as_float(((unsigned)h) << 16);
}

// async global->LDS, 16B per lane. LDS layout must be uniform_base + lane*16.
#define GLDS16(gp, lp) __builtin_amdgcn_global_load_lds( \
    (__attribute__((address_space(1))) unsigned int*)(gp), \
    (__attribute__((address_space(3))) unsigned int*)(lp), 16, 0, 0)

// ---------------------------------------------------------------------------
// Weight prep: W_effT[n][k] = qkv_w[k][n] + 2 * sum_r lora_a[k][r]*lora_b[r][n]
// ---------------------------------------------------------------------------
__global__ __launch_bounds__(256) void weff_kernel(
    const float* __restrict__ W, const float* __restrict__ la,
    const float* __restrict__ lb, unsigned short* __restrict__ Wt)
{
    __shared__ float tile[32][33];
    __shared__ float lat[32][16];
    __shared__ float lbt[16][32];
    const int kb = blockIdx.x * 32, nb = blockIdx.y * 32;
    const int tn = threadIdx.x & 31, tk = threadIdx.x >> 5;
    for (int i = threadIdx.x; i < 32 * 16; i += 256)
        lat[i >> 4][i & 15] = la[(size_t)(kb + (i >> 4)) * 16 + (i & 15)];
    for (int i = threadIdx.x; i < 16 * 32; i += 256)
        lbt[i >> 5][i & 31] = lb[(size_t)(i >> 5) * 3072 + nb + (i & 31)];
#pragma unroll
    for (int i = 0; i < 4; ++i) {
        int k = tk + i * 8;
        tile[k][tn] = W[(size_t)(kb + k) * 3072 + nb + tn];
    }
    __syncthreads();
#pragma unroll
    for (int i = 0; i < 4; ++i) {
        int n = tk + i * 8;
        float acc = tile[tn][n];
#pragma unroll
        for (int r = 0; r < 16; ++r) acc += 2.0f * lat[tn][r] * lbt[r][n];
        Wt[(size_t)(nb + n) * 1024 + kb + tn] = f2bf(acc);
    }
}

// ---------------------------------------------------------------------------
// Fused 3-way transpose: fp32 (KxN) -> bf16 (NxK) for proj_w / w1 / w2.
// ---------------------------------------------------------------------------
__global__ __launch_bounds__(256) void transpose3_kernel(
    const float* __restrict__ Wp, unsigned short* __restrict__ WpT,
    const float* __restrict__ W1, unsigned short* __restrict__ W1T,
    const float* __restrict__ W2, unsigned short* __restrict__ W2T)
{
    __shared__ float tile[32][33];
    const int id = blockIdx.x;
    const float* W; unsigned short* Wt; int Kdim, Ndim, kb, nb;
    if (id < 1024)      { W = Wp; Wt = WpT; Kdim = 1024; Ndim = 1024; const int t = id;        kb = t >> 5; nb = t & 31; }
    else if (id < 5120) { W = W1; Wt = W1T; Kdim = 1024; Ndim = 4096; const int t = id - 1024; kb = t >> 7; nb = t & 127; }
    else                { W = W2; Wt = W2T; Kdim = 4096; Ndim = 1024; const int t = id - 5120; kb = t >> 5; nb = t & 31; }
    kb <<= 5; nb <<= 5;
    const int tn = threadIdx.x & 31, tk = threadIdx.x >> 5;
#pragma unroll
    for (int i = 0; i < 4; ++i) {
        int k = tk + i * 8;
        tile[k][tn] = W[(size_t)(kb + k) * Ndim + nb + tn];
    }
    __syncthreads();
#pragma unroll
    for (int i = 0; i < 4; ++i) {
        int n = tk + i * 8;
        Wt[(size_t)(nb + n) * Kdim + kb + tn] = f2bf(tile[tn][n]);
    }
}

// ---------------------------------------------------------------------------
// LN1: x (2,64,64,1024) fp32 -> windowed bf16 (50*196, 1024); pad tokens = 0.
// ---------------------------------------------------------------------------
__global__ __launch_bounds__(256) void ln1_kernel(
    const float* __restrict__ x, const float* __restrict__ g,
    const float* __restrict__ b, unsigned short* __restrict__ out)
{
    const int blk = blockIdx.x;             // 0..9799
    const int tid = threadIdx.x;
    const int bw = blk / 196, tok = blk - bw * 196;
    const int bat = bw / 25, rw = bw - bat * 25;
    const int wy = rw / 5, wx = rw - wy * 5;
    const int ty = tok / 14, tx = tok - ty * 14;
    const int y = wy * 14 + ty, xx = wx * 14 + tx;
    unsigned short* orow = out + (size_t)blk * 1024;
    if (y >= 64 || xx >= 64) {
        *(uint2*)(orow + tid * 4) = make_uint2(0u, 0u);
        return;
    }
    const float* irow = x + ((size_t)((bat * 64 + y) * 64 + xx)) * 1024;
    const float4 v = *(const float4*)(irow + tid * 4);
    float s = v.x + v.y + v.z + v.w;
    float ss = v.x * v.x + v.y * v.y + v.z * v.z + v.w * v.w;
    for (int o = 32; o > 0; o >>= 1) { s += __shfl_xor(s, o); ss += __shfl_xor(ss, o); }
    __shared__ float red[8];
    const int wave = tid >> 6, lane = tid & 63;
    if (lane == 0) { red[wave] = s; red[4 + wave] = ss; }
    __syncthreads();
    s = red[0] + red[1] + red[2] + red[3];
    ss = red[4] + red[5] + red[6] + red[7];
    const float mu = s * (1.0f / 1024.0f);
    const float var = ss * (1.0f / 1024.0f) - mu * mu;
    const float rstd = rsqrtf(var + 1e-6f);
    const float4 gv = *(const float4*)(g + tid * 4);
    const float4 bv = *(const float4*)(b + tid * 4);
    const float a0 = (v.x - mu) * rstd * gv.x + bv.x;
    const float a1 = (v.y - mu) * rstd * gv.y + bv.y;
    const float a2 = (v.z - mu) * rstd * gv.z + bv.z;
    const float a3 = (v.w - mu) * rstd * gv.w + bv.w;
    const unsigned r0 = (unsigned)f2bf(a0) | ((unsigned)f2bf(a1) << 16);
    const unsigned r1 = (unsigned)f2bf(a2) | ((unsigned)f2bf(a3) << 16);
    *(uint2*)(orow + tid * 4) = make_uint2(r0, r1);
}

// LN2: rows of x1 (d_out, fp32) -> bf16, 8192 rows
__global__ __launch_bounds__(256) void ln2_kernel(
    const float* __restrict__ x, const float* __restrict__ g,
    const float* __restrict__ b, unsigned short* __restrict__ out)
{
    const int blk = blockIdx.x;
    const int tid = threadIdx.x;
    const float* irow = x + (size_t)blk * 1024;
    unsigned short* orow = out + (size_t)blk * 1024;
    const float4 v = *(const float4*)(irow + tid * 4);
    float s = v.x + v.y + v.z + v.w;
    float ss = v.x * v.x + v.y * v.y + v.z * v.z + v.w * v.w;
    for (int o = 32; o > 0; o >>= 1) { s += __shfl_xor(s, o); ss += __shfl_xor(ss, o); }
    __shared__ float red[8];
    const int wave = tid >> 6, lane = tid & 63;
    if (lane == 0) { red[wave] = s; red[4 + wave] = ss; }
    __syncthreads();
    s = red[0] + red[1] + red[2] + red[3];
    ss = red[4] + red[5] + red[6] + red[7];
    const float mu = s * (1.0f / 1024.0f);
    const float var = ss * (1.0f / 1024.0f) - mu * mu;
    const float rstd = rsqrtf(var + 1e-6f);
    const float4 gv = *(const float4*)(g + tid * 4);
    const float4 bv = *(const float4*)(b + tid * 4);
    const float a0 = (v.x - mu) * rstd * gv.x + bv.x;
    const float a1 = (v.y - mu) * rstd * gv.y + bv.y;
    const float a2 = (v.z - mu) * rstd * gv.z + bv.z;
    const float a3 = (v.w - mu) * rstd * gv.w + bv.w;
    const unsigned r0 = (unsigned)f2bf(a0) | ((unsigned)f2bf(a1) << 16);
    const unsigned r1 = (unsigned)f2bf(a2) | ((unsigned)f2bf(a3) << 16);
    *(uint2*)(orow + tid * 4) = make_uint2(r0, r1);
}

// ---------------------------------------------------------------------------
// gemm8p_v4: C[m][n] = sum_k A[m][k] * Bt[n][k]; BM=BN=256, BK=64, 512 thr.
// 4 phases/K-tile with B-register reuse (reads 8/4/8/4), counted vmcnt(2)
// mid+boundary, stage order {B01|B23|A02|A13}; LDS slot = chunk^(row&7)
// (0 conflicts, verified r3); inverse swizzle on per-lane global source.
// ---------------------------------------------------------------------------
template <int EPI>
__global__ __launch_bounds__(512, 2) void gemm8p_v4(
    const unsigned short* __restrict__ A,
    const unsigned short* __restrict__ Bt,
    const float* __restrict__ bias,
    void* __restrict__ outp,
    int M, int K, int nbm, int nbn)
{
    __shared__ unsigned short As_s[2 * 16384];
    __shared__ unsigned short Bs_s[2 * 16384];

    const int tid = threadIdx.x;
    const int wave = tid >> 6, lane = tid & 63;
    const int lr = lane & 15, lq = lane >> 4;

    const int ss = (nbm + 7) >> 3;
    const int xcd = blockIdx.x & 7;
    const int sidx = blockIdx.x >> 3;
    const int ntl = sidx / ss;
    const int m_loc = sidx - ntl * ss;
    const int mt = xcd * ss + m_loc;
    if (mt >= nbm) return;
    const int m_base = mt * 256, n_base = ntl * 256;
    const int NT = K >> 6;

    const int wm = (wave >> 2) * 128;           // 2 m-groups
    const int wn = (wave & 3) * 64;             // 4 n-groups

    // --- staging pointers: thread covers (row u*64 + tid>>3, slot tid&7) ---
    const int srow = tid >> 3, sslot = tid & 7;
    const int gch = sslot ^ (srow & 7);          // inverse swizzle on source
    const unsigned short* a_gp[4];
    const unsigned short* b_gp[4];
#pragma unroll
    for (int u = 0; u < 4; ++u) {
        int ar = m_base + u * 64 + srow; ar = ar < M ? ar : M - 1;
        a_gp[u] = A + (size_t)ar * K + gch * 8;
        b_gp[u] = Bt + (size_t)(n_base + u * 64 + srow) * K + gch * 8;
    }
#define STG_A(t, u) GLDS16(a_gp[u] + (size_t)(t) * 64, As_s + (((t) & 1) << 14) + (u) * 4096 + tid * 8)
#define STG_B(t, u) GLDS16(b_gp[u] + (size_t)(t) * 64, Bs_s + (((t) & 1) << 14) + (u) * 4096 + tid * 8)

    // --- fragment read offsets (shorts): row*64 + slot*8, slot = chunk^(lr&7)
    const int sl0 = lq ^ (lr & 7);               // kh0 slot; kh1 = sl0 ^ 4
    const int a_off = (wm + lr) * 64 + sl0 * 8;  // ^32 toggles k-half
    const int b_off = (wn + lr) * 64 + sl0 * 8;

    f32x4 acc[8][4] = {};

    // --- prologue: tile 0, {B all, A-u0,u2} first, then A-u1,u3 ---
    STG_B(0, 0); STG_B(0, 1); STG_B(0, 2); STG_B(0, 3);
    STG_A(0, 0); STG_A(0, 2);
    STG_A(0, 1); STG_A(0, 3);
    asm volatile("s_waitcnt vmcnt(2)" ::: "memory");
    __builtin_amdgcn_s_barrier();

    for (int t = 0; t < NT; ++t) {
        const unsigned short* Ab = As_s + ((t & 1) << 14);
        const unsigned short* Bb = Bs_s + ((t & 1) << 14);
        bf16x8 af[4], bfv[4];
        // ---- ph0: af[0..3] + bf, kh0; stage B-u0,u1(t+1); mid vmcnt ----
#pragma unroll
        for (int mf = 0; mf < 4; ++mf) af[mf] = *(const bf16x8*)(Ab + a_off + mf * 1024);
#pragma unroll
        for (int nf = 0; nf < 4; ++nf) bfv[nf] = *(const bf16x8*)(Bb + b_off + nf * 1024);
        if (t + 1 < NT) { STG_B(t + 1, 0); STG_B(t + 1, 1); }
        __builtin_amdgcn_s_barrier();
        asm volatile("s_waitcnt lgkmcnt(0)" ::: "memory");
        __builtin_amdgcn_sched_barrier(0);
        __builtin_amdgcn_s_setprio(1);
#pragma unroll
        for (int mf = 0; mf < 4; ++mf)
#pragma unroll
            for (int nf = 0; nf < 4; ++nf)
                acc[mf][nf] = __builtin_amdgcn_mfma_f32_16x16x32_bf16(af[mf], bfv[nf], acc[mf][nf], 0, 0, 0);
        __builtin_amdgcn_s_setprio(0);
        if (t == NT - 1) { asm volatile("s_waitcnt vmcnt(0)" ::: "memory"); }
        else             { asm volatile("s_waitcnt vmcnt(2)" ::: "memory"); }
        __builtin_amdgcn_s_barrier();
        // ---- ph1: af[4..7] kh0 (bfv reused); stage B-u2,u3(t+1) ----
#pragma unroll
        for (int mf = 0; mf < 4; ++mf) af[mf] = *(const bf16x8*)(Ab + a_off + (4 + mf) * 1024);
        if (t + 1 < NT) { STG_B(t + 1, 2); STG_B(t + 1, 3); }
        __builtin_amdgcn_s_barrier();
        asm volatile("s_waitcnt lgkmcnt(0)" ::: "memory");
        __builtin_amdgcn_sched_barrier(0);
        __builtin_amdgcn_s_setprio(1);
#pragma unroll
        for (int mf = 0; mf < 4; ++mf)
#pragma unroll
            for (int nf = 0; nf < 4; ++nf)
                acc[4 + mf][nf] = __builtin_amdgcn_mfma_f32_16x16x32_bf16(af[mf], bfv[nf], acc[4 + mf][nf], 0, 0, 0);
        __builtin_amdgcn_s_setprio(0);
        __builtin_amdgcn_s_barrier();
        // ---- ph2: af[0..3] + bf, kh1; stage A-u0,u2(t+1) ----
#pragma unroll
        for (int mf = 0; mf < 4; ++mf) af[mf] = *(const bf16x8*)(Ab + (a_off ^ 32) + mf * 1024);
#pragma unroll
        for (int nf = 0; nf < 4; ++nf) bfv[nf] = *(const bf16x8*)(Bb + (b_off ^ 32) + nf * 1024);
        if (t + 1 < NT) { STG_A(t + 1, 0); STG_A(t + 1, 2); }
        __builtin_amdgcn_s_barrier();
        asm volatile("s_waitcnt lgkmcnt(0)" ::: "memory");
        __builtin_amdgcn_sched_barrier(0);
        __builtin_amdgcn_s_setprio(1);
#pragma unroll
        for (int mf = 0; mf < 4; ++mf)
#pragma unroll
            for (int nf = 0; nf < 4; ++nf)
                acc[mf][nf] = __builtin_amdgcn_mfma_f32_16x16x32_bf16(af[mf], bfv[nf], acc[mf][nf], 0, 0, 0);
        __builtin_amdgcn_s_setprio(0);
        __builtin_amdgcn_s_barrier();
        // ---- ph3: af[4..7] kh1 (bfv reused); stage A-u1,u3(t+1); bnd vmcnt ----
#pragma unroll
        for (int mf = 0; mf < 4; ++mf) af[mf] = *(const bf16x8*)(Ab + (a_off ^ 32) + (4 + mf) * 1024);
        if (t + 1 < NT) { STG_A(t + 1, 1); STG_A(t + 1, 3); }
        __builtin_amdgcn_s_barrier();
        asm volatile("s_waitcnt lgkmcnt(0)" ::: "memory");
        __builtin_amdgcn_sched_barrier(0);
        __builtin_amdgcn_s_setprio(1);
#pragma unroll
        for (int mf = 0; mf < 4; ++mf)
#pragma unroll
            for (int nf = 0; nf < 4; ++nf)
                acc[4 + mf][nf] = __builtin_amdgcn_mfma_f32_16x16x32_bf16(af[mf], bfv[nf], acc[4 + mf][nf], 0, 0, 0);
        __builtin_amdgcn_s_setprio(0);
        if (t < NT - 1) { asm volatile("s_waitcnt vmcnt(2)" ::: "memory"); }
        __builtin_amdgcn_s_barrier();
    }
#undef STG_A
#undef STG_B

    // ------------------------------- epilogue -------------------------------
    float biasv[4];
#pragma unroll
    for (int j = 0; j < 4; ++j) biasv[j] = bias[n_base + wn + j * 16 + lr];

    if constexpr (EPI == 0) {
        // qkv scatter; V written transposed, packed 4 tokens (8B) per store.
        // 196 % 4 == 0 and row-starts % 4 == 0 -> 4-row chunk never straddles.
#pragma unroll
        for (int i = 0; i < 8; ++i) {
            const int m0i = m_base + wm + i * 16 + lq * 4;
            if (m0i >= M) continue;
            const int bw = m0i / 196, tok0 = m0i - bw * 196;
#pragma unroll
            for (int j = 0; j < 4; ++j) {
                const int n = n_base + wn + j * 16 + lr;
                const int which = n >> 10, hh = (n >> 6) & 15, d = n & 63;
                unsigned short* slotp = (unsigned short*)outp + (size_t)((bw * 3 + which) * 16 + hh) * 13312;
                if (which == 2) {
                    unsigned long long pv = 0;
#pragma unroll
                    for (int r = 0; r < 4; ++r)
                        pv |= (unsigned long long)f2bf(acc[i][j][r] + biasv[j]) << (16 * r);
                    *(unsigned long long*)(slotp + (size_t)d * 208 + tok0) = pv;
                } else {
#pragma unroll
                    for (int r = 0; r < 4; ++r)
                        slotp[(size_t)(tok0 + r) * 64 + d] = f2bf(acc[i][j][r] + biasv[j]);
                }
            }
        }
    } else {
        // EPI == 2: fast tanh-GELU -> bf16 [M][4096]
#pragma unroll
        for (int i = 0; i < 8; ++i) {
#pragma unroll
            for (int r = 0; r < 4; ++r) {
                const int m = m_base + wm + i * 16 + lq * 4 + r;
                if (m >= M) continue;
#pragma unroll
                for (int j = 0; j < 4; ++j) {
                    const int n = n_base + wn + j * 16 + lr;
                    const float v = acc[i][j][r] + biasv[j];
                    const float t2 = 1.5957691216f * (v + 0.044715f * v * v * v);
                    const float e = __expf(-t2);
                    const float gl = v * __builtin_amdgcn_rcpf(1.0f + e);
                    ((unsigned short*)outp)[(size_t)m * 4096 + n] = f2bf(gl);
                }
            }
        }
    }
}

// ---------------------------------------------------------------------------
// Proven 128-tile 2-barrier GEMM (m97 structure) — proj.
// EPI=1: proj (bias + residual + window-unpartition, fp32 out).
// ---------------------------------------------------------------------------
template <int EPI>
__global__ __launch_bounds__(256) void gemm_kernel(
    const unsigned short* __restrict__ A,
    const unsigned short* __restrict__ Bt,
    const float* __restrict__ bias,
    void* __restrict__ outp,
    const float* __restrict__ aux,
    int M, int K, int nbm, int nbn)
{
    __shared__ unsigned short As[2][128 * 32];
    __shared__ unsigned short Bs[2][128 * 32];
    const int tid = threadIdx.x;
    const int wave = tid >> 6, lane = tid & 63;
    const int lr = lane & 15, lq = lane >> 4;
    const int ss = (nbm + 7) >> 3;
    const int xcd = blockIdx.x & 7;
    const int s = blockIdx.x >> 3;
    const int nt = s / ss;
    const int m_loc = s - nt * ss;
    const int mt = xcd * ss + m_loc;
    if (mt >= nbm) return;
    const int m_base = mt * 128, n_base = nt * 128;
    const int wm = (wave >> 1) * 64, wn = (wave & 1) * 64;
    const int N = nbn * 128;

    const int c0 = tid, c1 = tid + 256;
    const int row0 = c0 >> 2, row1 = c1 >> 2;
    const int kc = (tid & 3) ^ ((tid >> 3) & 3);
    int ar0 = m_base + row0; ar0 = ar0 < M ? ar0 : M - 1;
    int ar1 = m_base + row1; ar1 = ar1 < M ? ar1 : M - 1;
    int br0 = n_base + row0; br0 = br0 < N ? br0 : N - 1;
    int br1 = n_base + row1; br1 = br1 < N ? br1 : N - 1;
    const unsigned short* agp0 = A + (size_t)ar0 * K + kc * 8;
    const unsigned short* agp1 = A + (size_t)ar1 * K + kc * 8;
    const unsigned short* bgp0 = Bt + (size_t)br0 * K + kc * 8;
    const unsigned short* bgp1 = Bt + (size_t)br1 * K + kc * 8;
    unsigned short* alp0 = As[0] + c0 * 8;
    unsigned short* alp1 = As[0] + c1 * 8;
    unsigned short* blp0 = Bs[0] + c0 * 8;
    unsigned short* blp1 = Bs[0] + c1 * 8;
    unsigned short* alp0b = As[1] + c0 * 8;
    unsigned short* alp1b = As[1] + c1 * 8;
    unsigned short* blp0b = Bs[1] + c0 * 8;
    unsigned short* blp1b = Bs[1] + c1 * 8;

    const int swz = (lq ^ ((lr >> 1) & 3)) * 8;

    f32x4 acc[4][4] = {};

    for (int k0 = 0; k0 < K; k0 += 64) {
        GLDS16(agp0 + k0, alp0);
        GLDS16(agp1 + k0, alp1);
        GLDS16(bgp0 + k0, blp0);
        GLDS16(bgp1 + k0, blp1);
        GLDS16(agp0 + k0 + 32, alp0b);
        GLDS16(agp1 + k0 + 32, alp1b);
        GLDS16(bgp0 + k0 + 32, blp0b);
        GLDS16(bgp1 + k0 + 32, blp1b);
        __syncthreads();
#pragma unroll
        for (int half = 0; half < 2; ++half) {
            bf16x8 af[4], bfr[4];
#pragma unroll
            for (int i = 0; i < 4; ++i) {
                af[i]  = *(const bf16x8*)(As[half] + (wm + i * 16 + lr) * 32 + swz);
                bfr[i] = *(const bf16x8*)(Bs[half] + (wn + i * 16 + lr) * 32 + swz);
            }
#pragma unroll
            for (int i = 0; i < 4; ++i)
#pragma unroll
                for (int j = 0; j < 4; ++j)
                    acc[i][j] = __builtin_amdgcn_mfma_f32_16x16x32_bf16(af[i], bfr[j], acc[i][j], 0, 0, 0);
        }
        __syncthreads();
    }

    float biasv[4];
#pragma unroll
    for (int j = 0; j < 4; ++j) biasv[j] = bias[n_base + wn + j * 16 + lr];

#pragma unroll
    for (int i = 0; i < 4; ++i) {
#pragma unroll
        for (int r = 0; r < 4; ++r) {
            const int m = m_base + wm + i * 16 + lq * 4 + r;
            if (m >= M) continue;
            int y = 0, xx = 0, b = 0;
            if constexpr (EPI == 1) {
                const int bw = m / 196, tok = m - bw * 196;
                b = bw / 25;
                const int rw = bw - b * 25;
                const int wy = rw / 5, wx = rw - wy * 5;
                const int ty = tok / 14, tx = tok - ty * 14;
                y = wy * 14 + ty; xx = wx * 14 + tx;
            }
#pragma unroll
            for (int j = 0; j < 4; ++j) {
                const int n = n_base + wn + j * 16 + lr;
                const float v = acc[i][j][r] + biasv[j];
                if constexpr (EPI == 1) {
                    if (y < 64 && xx < 64) {
                        const size_t idx = ((size_t)((b * 64 + y) * 64 + xx)) * 1024 + n;
                        ((float*)outp)[idx] = aux[idx] + v;
                    }
                } else {
                    const size_t idx = (size_t)m * 1024 + n;
                    ((float*)outp)[idx] += v;
                }
            }
        }
    }
}

// ---------------------------------------------------------------------------
// gemm_db_kernel (r10, MLP-down): 128² tile, cross-K-tile double-buffer with
// counted vmcnt. Per iteration t: STAGE(t+1) into buf[(t+1)&1] (8 GLDS) ->
// s_waitcnt vmcnt(8) (retires tile t's loads issued last iteration; t+1's 8
// stay in flight across the barrier) -> raw s_barrier -> compute tile t ->
// s_barrier. Last tile: vmcnt(0). WAR safe: STAGE(t+2) (at iter t+1) targets
// buf[t&1], whose readers all passed iter-t's end barrier (their ds_reads are
// consumed by MFMAs preceding it). LDS 64 KB -> still 2 blocks/CU (grid 512).
// Epilogue: bias + plain += onto fp32 out (one writer per element).
// ---------------------------------------------------------------------------
__global__ __launch_bounds__(256) void gemm_db_kernel(
    const unsigned short* __restrict__ A,
    const unsigned short* __restrict__ Bt,
    const float* __restrict__ bias,
    float* __restrict__ outp,
    int M, int K, int nbm, int nbn)
{
    __shared__ unsigned short As[2][2][128 * 32];   // [tile parity][k-half]
    __shared__ unsigned short Bs[2][2][128 * 32];
    const int tid = threadIdx.x;
    const int wave = tid >> 6, lane = tid & 63;
    const int lr = lane & 15, lq = lane >> 4;
    const int ss = (nbm + 7) >> 3;
    const int xcd = blockIdx.x & 7;
    const int s = blockIdx.x >> 3;
    const int nt = s / ss;
    const int m_loc = s - nt * ss;
    const int mt = xcd * ss + m_loc;
    if (mt >= nbm) return;
    const int m_base = mt * 128, n_base = nt * 128;
    const int wm = (wave >> 1) * 64, wn = (wave & 1) * 64;
    const int N = nbn * 128;

    const int c0 = tid, c1 = tid + 256;
    const int row0 = c0 >> 2, row1 = c1 >> 2;
    const int kc = (tid & 3) ^ ((tid >> 3) & 3);
    int ar0 = m_base + row0; ar0 = ar0 < M ? ar0 : M - 1;
    int ar1 = m_base + row1; ar1 = ar1 < M ? ar1 : M - 1;
    int br0 = n_base + row0; br0 = br0 < N ? br0 : N - 1;
    int br1 = n_base + row1; br1 = br1 < N ? br1 : N - 1;
    const unsigned short* agp0 = A + (size_t)ar0 * K + kc * 8;
    const unsigned short* agp1 = A + (size_t)ar1 * K + kc * 8;
    const unsigned short* bgp0 = Bt + (size_t)br0 * K + kc * 8;
    const unsigned short* bgp1 = Bt + (size_t)br1 * K + kc * 8;

#define STAGE_DB(tt) do { \
        const int _par = (tt) & 1; \
        const size_t _ko = (size_t)(tt) * 64; \
        GLDS16(agp0 + _ko,      As[_par][0] + c0 * 8); \
        GLDS16(agp1 + _ko,      As[_par][0] + c1 * 8); \
        GLDS16(bgp0 + _ko,      Bs[_par][0] + c0 * 8); \
        GLDS16(bgp1 + _ko,      Bs[_par][0] + c1 * 8); \
        GLDS16(agp0 + _ko + 32, As[_par][1] + c0 * 8); \
        GLDS16(agp1 + _ko + 32, As[_par][1] + c1 * 8); \
        GLDS16(bgp0 + _ko + 32, Bs[_par][1] + c0 * 8); \
        GLDS16(bgp1 + _ko + 32, Bs[_par][1] + c1 * 8); \
    } while (0)

    const int swz = (lq ^ ((lr >> 1) & 3)) * 8;

    f32x4 acc[4][4] = {};
    const int NT = K >> 6;

    STAGE_DB(0);
    for (int t = 0; t < NT; ++t) {
        if (t + 1 < NT) {
            STAGE_DB(t + 1);
            asm volatile("s_waitcnt vmcnt(8)" ::: "memory");
        } else {
            asm volatile("s_waitcnt vmcnt(0)" ::: "memory");
        }
        __builtin_amdgcn_s_barrier();
        const int par = t & 1;
#pragma unroll
        for (int half = 0; half < 2; ++half) {
            bf16x8 af[4], bfr[4];
#pragma unroll
            for (int i = 0; i < 4; ++i) {
                af[i]  = *(const bf16x8*)(As[par][half] + (wm + i * 16 + lr) * 32 + swz);
                bfr[i] = *(const bf16x8*)(Bs[par][half] + (wn + i * 16 + lr) * 32 + swz);
            }
#pragma unroll
            for (int i = 0; i < 4; ++i)
#pragma unroll
                for (int j = 0; j < 4; ++j)
                    acc[i][j] = __builtin_amdgcn_mfma_f32_16x16x32_bf16(af[i], bfr[j], acc[i][j], 0, 0, 0);
        }
        __builtin_amdgcn_s_barrier();
    }
#undef STAGE_DB

    float biasv[4];
#pragma unroll
    for (int j = 0; j < 4; ++j) biasv[j] = bias[n_base + wn + j * 16 + lr];

#pragma unroll
    for (int i = 0; i < 4; ++i) {
#pragma unroll
        for (int r = 0; r < 4; ++r) {
            const int m = m_base + wm + i * 16 + lq * 4 + r;
            if (m >= M) continue;
#pragma unroll
            for (int j = 0; j < 4; ++j) {
                const int n = n_base + wn + j * 16 + lr;
                outp[(size_t)m * 1024 + n] += acc[i][j][r] + biasv[j];
            }
        }
    }
}

// ---------------------------------------------------------------------------
// Windowed attention v2 (proven). Grid = 800 (window*head), 256 threads /
// 4 waves, 2 blocks/CU (LDS 70.4 KB). Vt LDS staging retained: it is the
// transpose/coalescing layer for the PV MFMA B-operand (r8 evidence).
// ---------------------------------------------------------------------------
__global__ __launch_bounds__(256, 2) void attn_kernel(
    const unsigned short* __restrict__ qkv,
    const float* __restrict__ relh, const float* __restrict__ relw,
    unsigned short* __restrict__ attn_out)
{
    __shared__ unsigned short Vt[64][232];     // V^T staged (cols 0..231 from global)
    __shared__ unsigned short Pst[4][16][232]; // per-wave P strip (A-layout via LDS)
    __shared__ unsigned short Db[196][28];     // rel bias: [m][0..13]=h, [14..27]=w

    const int tid = threadIdx.x;
    const int wave = tid >> 6, lane = tid & 63;
    const int lr = lane & 15, lq = lane >> 4;
    const int bw = blockIdx.x >> 4, h = blockIdx.x & 15;
    const unsigned short* qp = qkv + (size_t)((bw * 3 + 0) * 16 + h) * 13312;
    const unsigned short* kp = qkv + (size_t)((bw * 3 + 1) * 16 + h) * 13312;
    const unsigned short* vp = qkv + (size_t)((bw * 3 + 2) * 16 + h) * 13312;

    // zero this wave's Pst pad cols [208,224) once (never overwritten later)
    *(uint2*)&Pst[wave][lane >> 2][208 + (lane & 3) * 4] = make_uint2(0u, 0u);

    // stage V^T: 64 rows x 232 cols (29 x 16B chunks per row) async from global
    {
        unsigned short* vtf = &Vt[0][0];
        for (int idx = tid; idx < 64 * 29; idx += 256) {
            const int d = idx / 29, c = idx - d * 29;
            GLDS16(vp + d * 208 + c * 8, vtf + idx * 8);
        }
    }

    // rel-pos bias via MFMA: 28 tasks = (h:14 coords, w:14 coords)
    for (int t = wave; t < 28; t += 4) {
        const int isw = t >= 14;
        const int c = isw ? t - 14 : t;
        const int arow = isw ? (lr * 14 + c) : (c * 14 + lr);
        const unsigned short* ap = qp + arow * 64 + lq * 8;
        const bf16x8 a0 = *(const bf16x8*)ap;
        const bf16x8 a1 = *(const bf16x8*)(ap + 32);
        int ridx = c - lr + 13;
        ridx = ridx < 0 ? 0 : (ridx > 26 ? 26 : ridx);
        const float* tb = (isw ? relw : relh) + ridx * 64 + lq * 8;
        union BV { unsigned short u[8]; bf16x8 v; } b0, b1;
        {
            const float4 x0 = *(const float4*)tb;
            const float4 x1 = *(const float4*)(tb + 4);
            b0.u[0] = f2bf(x0.x); b0.u[1] = f2bf(x0.y); b0.u[2] = f2bf(x0.z); b0.u[3] = f2bf(x0.w);
            b0.u[4] = f2bf(x1.x); b0.u[5] = f2bf(x1.y); b0.u[6] = f2bf(x1.z); b0.u[7] = f2bf(x1.w);
            const float4 x2 = *(const float4*)(tb + 32);
            const float4 x3 = *(const float4*)(tb + 36);
            b1.u[0] = f2bf(x2.x); b1.u[1] = f2bf(x2.y); b1.u[2] = f2bf(x2.z); b1.u[3] = f2bf(x2.w);
            b1.u[4] = f2bf(x3.x); b1.u[5] = f2bf(x3.y); b1.u[6] = f2bf(x3.z); b1.u[7] = f2bf(x3.w);
        }
        f32x4 dacc = {};
        dacc = __builtin_amdgcn_mfma_f32_16x16x32_bf16(a0, b0.v, dacc, 0, 0, 0);
        dacc = __builtin_amdgcn_mfma_f32_16x16x32_bf16(a1, b1.v, dacc, 0, 0, 0);
#pragma unroll
        for (int r = 0; r < 4; ++r) {
            const int y = lq * 4 + r;
            if (y < 14 && lr < 14) {
                const int g = isw ? y * 14 + c : c * 14 + y;
                Db[g][isw ? 14 + lr : lr] = f2bf(dacc[r]);
            }
        }
    }
    __syncthreads();

    for (int mt = wave; mt < 13; mt += 4) {
        const int m0 = mt * 16;
        const unsigned short* qb = qp + (size_t)(m0 + lr) * 64 + lq * 8;
        const bf16x8 qa0 = *(const bf16x8*)qb;
        const bf16x8 qa1 = *(const bf16x8*)(qb + 32);
        f32x4 sc[13];
#pragma unroll
        for (int nt = 0; nt < 13; ++nt) {
            const unsigned short* kb = kp + (size_t)(nt * 16 + lr) * 64 + lq * 8;
            const bf16x8 k0 = *(const bf16x8*)kb;
            const bf16x8 k1 = *(const bf16x8*)(kb + 32);
            f32x4 a = {};
            a = __builtin_amdgcn_mfma_f32_16x16x32_bf16(qa0, k0, a, 0, 0, 0);
            a = __builtin_amdgcn_mfma_f32_16x16x32_bf16(qa1, k1, a, 0, 0, 0);
            sc[nt] = a;
        }
        int grow[4];
#pragma unroll
        for (int r = 0; r < 4; ++r) {
            int g = m0 + lq * 4 + r;
            grow[r] = g > 195 ? 195 : g;
        }
#pragma unroll
        for (int nt = 0; nt < 13; ++nt) {
            const int n = nt * 16 + lr;
            if (n < 196) {
                const int nx = n / 14, ny = n - nx * 14;
#pragma unroll
                for (int r = 0; r < 4; ++r)
                    sc[nt][r] = sc[nt][r] * 0.125f + bf2f(Db[grow[r]][nx]) + bf2f(Db[grow[r]][14 + ny]);
            } else {
#pragma unroll
                for (int r = 0; r < 4; ++r) sc[nt][r] = -1e30f;
            }
        }
        float rs[4];
#pragma unroll
        for (int r = 0; r < 4; ++r) {
            float mx = sc[0][r];
#pragma unroll
            for (int nt = 1; nt < 13; ++nt) mx = fmaxf(mx, sc[nt][r]);
            mx = fmaxf(mx, __shfl_xor(mx, 1));
            mx = fmaxf(mx, __shfl_xor(mx, 2));
            mx = fmaxf(mx, __shfl_xor(mx, 4));
            mx = fmaxf(mx, __shfl_xor(mx, 8));
            float s = 0.f;
#pragma unroll
            for (int nt = 0; nt < 13; ++nt) {
                const float e = __expf(sc[nt][r] - mx);
                sc[nt][r] = e;
                s += e;
            }
            s += __shfl_xor(s, 1);
            s += __shfl_xor(s, 2);
            s += __shfl_xor(s, 4);
            s += __shfl_xor(s, 8);
            rs[r] = 1.0f / s;
        }
#pragma unroll
        for (int nt = 0; nt < 13; ++nt)
#pragma unroll
            for (int r = 0; r < 4; ++r)
                Pst[wave][lq * 4 + r][nt * 16 + lr] = f2bf(sc[nt][r]);
#pragma unroll
        for (int dt = 0; dt < 4; ++dt) {
            f32x4 a = {};
#pragma unroll
            for (int ks = 0; ks < 7; ++ks) {
                const bf16x8 pa = *(const bf16x8*)&Pst[wave][lr][ks * 32 + lq * 8];
                const bf16x8 vb = *(const bf16x8*)&Vt[dt * 16 + lr][ks * 32 + lq * 8];
                a = __builtin_amdgcn_mfma_f32_16x16x32_bf16(pa, vb, a, 0, 0, 0);
            }
#pragma unroll
            for (int r = 0; r < 4; ++r) {
                const int m = m0 + lq * 4 + r;
                if (m < 196)
                    attn_out[(size_t)(bw * 196 + m) * 1024 + h * 64 + dt * 16 + lr] = f2bf(a[r] * rs[r]);
            }
        }
    }
}

// ---------------------------------------------------------------------------
extern "C" void kernel_launch(void* const* d_in, const int* in_sizes, int n_in,
                              void* d_out, int out_size, void* d_ws, size_t ws_size,
                              hipStream_t stream)
{
    (void)in_sizes; (void)n_in; (void)out_size; (void)ws_size;
    const float* x      = (const float*)d_in[0];
    const float* n1g    = (const float*)d_in[1];
    const float* n1b    = (const float*)d_in[2];
    const float* qkv_w  = (const float*)d_in[3];
    const float* qkv_b  = (const float*)d_in[4];
    const float* lora_a = (const float*)d_in[5];
    const float* lora_b = (const float*)d_in[6];
    const float* relh   = (const float*)d_in[7];
    const float* relw   = (const float*)d_in[8];
    const float* proj_w = (const float*)d_in[9];
    const float* proj_b = (const float*)d_in[10];
    const float* n2g    = (const float*)d_in[11];
    const float* n2b    = (const float*)d_in[12];
    const float* w1     = (const float*)d_in[13];
    const float* b1     = (const float*)d_in[14];
    const float* w2     = (const float*)d_in[15];
    const float* b2     = (const float*)d_in[16];
    float* out = (float*)d_out;

    char* ws = (char*)d_ws;
    size_t off = 0;
    auto alloc = [&](size_t bytes) {
        char* p = ws + off;
        off += (bytes + 255) & ~(size_t)255;
        return p;
    };
    unsigned short* weffT = (unsigned short*)alloc((size_t)3072 * 1024 * 2);
    unsigned short* projT = (unsigned short*)alloc((size_t)1024 * 1024 * 2);
    unsigned short* w1T   = (unsigned short*)alloc((size_t)4096 * 1024 * 2);
    unsigned short* w2T   = (unsigned short*)alloc((size_t)1024 * 4096 * 2);
    unsigned short* xnw   = (unsigned short*)alloc((size_t)9800 * 1024 * 2); // later reused as xn2
    unsigned short* qkvb  = (unsigned short*)alloc((size_t)8192 * 4096 * 2); // qkv slots / later hmid
    unsigned short* attno = (unsigned short*)alloc((size_t)9800 * 1024 * 2);

    // weight prep (bf16, transposed to NxK): weff + fused 3-way transpose
    weff_kernel<<<dim3(32, 96), 256, 0, stream>>>(qkv_w, lora_a, lora_b, weffT);
    transpose3_kernel<<<9216, 256, 0, stream>>>(proj_w, projT, w1, w1T, w2, w2T);
    // LN1 into windowed bf16 layout (pad tokens zeroed)
    ln1_kernel<<<9800, 256, 0, stream>>>(x, n1g, n1b, xnw);
    // QKV (+LoRA folded), scatter to padded slots (V pre-transposed)
    // v4: nbm=39, ss=5, nbn=12 -> grid 480
    gemm8p_v4<0><<<dim3(8 * 5 * 12), 512, 0, stream>>>(xnw, weffT, qkv_b, qkvb, 9800, 1024, 39, 12);
    // windowed attention (Vt staged, 2 blocks/CU — proven)
    attn_kernel<<<800, 256, 0, stream>>>(qkvb, relh, relw, attno);
    // proj + bias + residual + unpartition -> d_out holds x1 (128-tile, proven)
    gemm_kernel<1><<<dim3(8 * 10 * 8), 256, 0, stream>>>(attno, projT, proj_b, out, x, 9800, 1024, 77, 8);
    // LN2
    unsigned short* xn2 = xnw;
    ln2_kernel<<<8192, 256, 0, stream>>>(out, n2g, n2b, xn2);
    // MLP up (v4): nbm=32, ss=4, nbn=16 -> grid 512
    unsigned short* hmid = qkvb;
    gemm8p_v4<2><<<dim3(8 * 4 * 16), 512, 0, stream>>>(xn2, w1T, b1, hmid, 8192, 1024, 32, 16);
    // MLP down: 128² double-buffered counted-vmcnt (nbm=64, ss=8, nbn=8 -> grid 512)
    gemm_db_kernel<<<dim3(8 * 8 * 8), 256, 0, stream>>>(hmid, w2T, b2, out, 8192, 4096, 64, 8);
}